// Round 9
// baseline (240.278 us; speedup 1.0000x reference)
//
#include <hip/hip_runtime.h>
#include <math.h>

#define N_NODES 50000
#define N_EDGES 800000
#define N_CAND  100000
#define D       128
#define BN_EPS  1e-5f
#define SLOPE   0.01f

// tiled-binning CSR build
#define NB2     196      // coarse buckets of 256 nodes (d >> 8), covers 50176
#define TILE    4096     // edges per k_bin block
#define NTILE   196      // 196 * 4096 = 802816 >= E
#define BCAP    4736     // per-bucket capacity: mean 4096, +10 sigma

typedef __attribute__((ext_vector_type(8))) short bf16x8;
typedef __attribute__((ext_vector_type(4))) float f32x4;

__device__ __forceinline__ float lrelu(float x){ return x >= 0.f ? x : SLOPE * x; }

__device__ __forceinline__ unsigned short f2bf_rn(float f){
  unsigned int u = __float_as_uint(f);
  unsigned int r = u + 0x7FFFu + ((u >> 16) & 1u);
  return (unsigned short)(r >> 16);
}
__device__ __forceinline__ float bf2f(unsigned short h){
  return __uint_as_float(((unsigned int)h) << 16);
}
__device__ __forceinline__ float4 bf4f(ushort4 u){
  return make_float4(__uint_as_float((unsigned)u.x << 16),
                     __uint_as_float((unsigned)u.y << 16),
                     __uint_as_float((unsigned)u.z << 16),
                     __uint_as_float((unsigned)u.w << 16));
}

// pack 2 f32 -> 2 bf16 in one inst ([15:0]=bf16(a), [31:16]=bf16(b))
__device__ __forceinline__ unsigned pk_bf16(float a, float b){
  unsigned r;
  asm("v_cvt_pk_bf16_f32 %0, %1, %2" : "=v"(r) : "v"(a), "v"(b));
  return r;
}
// split pair into hi + lo ( lo = rn(x - hi) -> self-correcting wrt cvt rounding )
__device__ __forceinline__ void split2(float a, float b, unsigned &h, unsigned &l){
  h = pk_bf16(a, b);
  float ra = a - __uint_as_float(h << 16);
  float rb = b - __uint_as_float(h & 0xffff0000u);
  l = pk_bf16(ra, rb);
}
// split a float4-pair (8 consecutive k) into A-fragment hi/lo
__device__ __forceinline__ void split8(const float4 &v0, const float4 &v1, uint4 &h, uint4 &l){
  split2(v0.x, v0.y, h.x, l.x);
  split2(v0.z, v0.w, h.y, l.y);
  split2(v1.x, v1.y, h.z, l.z);
  split2(v1.z, v1.w, h.w, l.w);
}

// ---------------- CSR build: LDS-staged tiled binning ----------------
__global__ __launch_bounds__(256) void k_bin(const int* __restrict__ src, const int* __restrict__ dst,
                                             int* __restrict__ gcnt, unsigned* __restrict__ ebin, int E){
  __shared__ unsigned stage[TILE];
  __shared__ int hist[256], lscan[256], lex[256], lcur[256], gbase[256];
  __shared__ int stot;
  int t = threadIdx.x;
  int e0 = blockIdx.x * TILE;

  hist[t] = 0;
  __syncthreads();

  unsigned pk[16]; int bk[16]; bool ok[16];
  #pragma unroll
  for (int j = 0; j < 16; ++j){
    int i = e0 + j * 256 + t;
    ok[j] = (i < E);
    if (ok[j]){
      int d = dst[i];
      pk[j] = ((unsigned)d << 16) | (unsigned)src[i];
      bk[j] = d >> 8;
      atomicAdd(&hist[bk[j]], 1);
    }
  }
  __syncthreads();

  // inclusive scan of hist -> lscan
  lscan[t] = hist[t];
  __syncthreads();
  for (int off = 1; off < 256; off <<= 1){
    int v = (t >= off) ? lscan[t - off] : 0;
    __syncthreads();
    lscan[t] += v;
    __syncthreads();
  }
  int ex = lscan[t] - hist[t];
  lex[t]  = ex;
  lcur[t] = ex;
  if (t < NB2) gbase[t] = hist[t] ? atomicAdd(&gcnt[t], hist[t]) : 0;
  if (t == 255) stot = lscan[255];
  __syncthreads();

  // scatter tile into LDS, ordered by bucket
  #pragma unroll
  for (int j = 0; j < 16; ++j){
    if (ok[j]){
      int p = atomicAdd(&lcur[bk[j]], 1);
      stage[p] = pk[j];
    }
  }
  __syncthreads();

  // burst write: runs are contiguous in both LDS and global
  int tot = stot;
  for (int i = t; i < tot; i += 256){
    unsigned e = stage[i];
    int b = (int)(e >> 24);
    ebin[(size_t)b * BCAP + gbase[b] + (i - lex[b])] = e;
  }
}

// Pass B: exclusive scan of bucket totals -> bbase; rowptr[N] = E.
__global__ __launch_bounds__(256) void k_bscan2(const int* __restrict__ gcnt, int* __restrict__ bbase,
                                                int* __restrict__ rowptr){
  __shared__ int sd[256];
  int t = threadIdx.x;
  int v = (t < NB2) ? gcnt[t] : 0;
  sd[t] = v; __syncthreads();
  for (int off = 1; off < 256; off <<= 1){
    int a = (t >= off) ? sd[t - off] : 0;
    __syncthreads();
    sd[t] += a; __syncthreads();
  }
  if (t < NB2) bbase[t] = sd[t] - v;
  if (t == NB2 - 1) rowptr[N_NODES] = sd[t];
}

// Pass C: per-bucket counting sort over its 256 nodes -> rowptr + eid16.
__global__ __launch_bounds__(256) void k_bfin(const int* __restrict__ gcnt, const int* __restrict__ bbase,
                                              const unsigned* __restrict__ ebin,
                                              unsigned short* __restrict__ eid16,
                                              int* __restrict__ rowptr, int n){
  __shared__ int hist[256], lb[256], lcur[256];
  int t = threadIdx.x, b = blockIdx.x;
  int cb   = gcnt[b];
  int base = bbase[b];
  const unsigned* eb = &ebin[(size_t)b * BCAP];
  hist[t] = 0;
  __syncthreads();
  for (int idx = t; idx < cb; idx += 256) atomicAdd(&hist[(eb[idx] >> 16) & 255], 1);
  __syncthreads();
  lb[t] = hist[t];
  __syncthreads();
  for (int off = 1; off < 256; off <<= 1){
    int v = (t >= off) ? lb[t - off] : 0;
    __syncthreads();
    lb[t] += v; __syncthreads();
  }
  int ex = lb[t] - hist[t];
  lcur[t] = ex;
  int node = (b << 8) + t;
  if (node < n) rowptr[node] = base + ex;
  __syncthreads();
  for (int idx = t; idx < cb; idx += 256){
    unsigned e = eb[idx];
    int p = atomicAdd(&lcur[(e >> 16) & 255], 1);
    eid16[base + p] = (unsigned short)(e & 0xffffu);
  }
}

// ---------------- weight transpose + bf16 hi/lo split (SAGE) ----------------
__global__ __launch_bounds__(256) void k_cvt_w(const float* __restrict__ ws, const float* __restrict__ wn,
                                               unsigned short* __restrict__ bth, unsigned short* __restrict__ btl){
  int col = blockIdx.x;       // 0..127
  int k   = threadIdx.x;      // 0..255
  float v = (k < 128) ? ws[k * D + col] : wn[(k - 128) * D + col];
  unsigned short hi = f2bf_rn(v);
  unsigned short lo = f2bf_rn(v - bf2f(hi));
  bth[col * 256 + k] = hi;
  btl[col * 256 + k] = lo;
}

// ---------------- MLP weight transpose + split: w[K x 64] -> T_h/T_l [64][Kpad] ----------------
__global__ __launch_bounds__(256) void k_cvt_mlp(const float* __restrict__ w, int K, int Kpad,
                                                 unsigned short* __restrict__ th, unsigned short* __restrict__ tl){
  int col = blockIdx.x;       // 0..63
  for (int k = threadIdx.x; k < Kpad; k += 256){
    float v = (k < K) ? w[k * 64 + col] : 0.f;
    unsigned short hi = f2bf_rn(v);
    th[col * Kpad + k] = hi;
    tl[col * Kpad + k] = f2bf_rn(v - bf2f(hi));
  }
}

// ---------------- x -> bf16 plane ----------------
__global__ __launch_bounds__(256) void k_cvt_x(const float* __restrict__ X, unsigned short* __restrict__ XB, int nel4){
  int i = blockIdx.x * 256 + threadIdx.x;
  if (i < nel4){
    float4 v = *reinterpret_cast<const float4*>(&X[(size_t)i * 4]);
    ushort4 u;
    u.x = f2bf_rn(v.x); u.y = f2bf_rn(v.y); u.z = f2bf_rn(v.z); u.w = f2bf_rn(v.w);
    *reinterpret_cast<ushort4*>(&XB[(size_t)i * 4]) = u;
  }
}

// ---------------- mean aggregation: bf16 gather, fp32 accumulate ----------------
// x4 unroll with independent accumulators: 4 neighbor rows in flight per
// 32-lane group (attacks L3-gather latency; VALUBusy was 10%).
__global__ __launch_bounds__(256) void k_agg_bf(const unsigned short* __restrict__ XB,
                                                const int* __restrict__ rowptr, const unsigned short* __restrict__ eid,
                                                float* __restrict__ AG, int n){
  int g = blockIdx.x * 8 + (threadIdx.x >> 5);   // node
  int l = threadIdx.x & 31;                      // 4-bf16 chunk
  if (g >= n) return;
  int e0 = rowptr[g], e1 = rowptr[g + 1];
  float4 a0 = make_float4(0.f,0.f,0.f,0.f);
  float4 a1 = make_float4(0.f,0.f,0.f,0.f);
  float4 a2 = make_float4(0.f,0.f,0.f,0.f);
  float4 a3 = make_float4(0.f,0.f,0.f,0.f);
  int e = e0;
  for (; e + 4 <= e1; e += 4){
    int s0 = eid[e], s1 = eid[e + 1], s2 = eid[e + 2], s3 = eid[e + 3];
    ushort4 u0 = *reinterpret_cast<const ushort4*>(&XB[(size_t)s0 * D + l * 4]);
    ushort4 u1 = *reinterpret_cast<const ushort4*>(&XB[(size_t)s1 * D + l * 4]);
    ushort4 u2 = *reinterpret_cast<const ushort4*>(&XB[(size_t)s2 * D + l * 4]);
    ushort4 u3 = *reinterpret_cast<const ushort4*>(&XB[(size_t)s3 * D + l * 4]);
    float4 f0 = bf4f(u0), f1 = bf4f(u1), f2 = bf4f(u2), f3 = bf4f(u3);
    a0.x += f0.x; a0.y += f0.y; a0.z += f0.z; a0.w += f0.w;
    a1.x += f1.x; a1.y += f1.y; a1.z += f1.z; a1.w += f1.w;
    a2.x += f2.x; a2.y += f2.y; a2.z += f2.z; a2.w += f2.w;
    a3.x += f3.x; a3.y += f3.y; a3.z += f3.z; a3.w += f3.w;
  }
  for (; e < e1; ++e){
    int s0 = eid[e];
    ushort4 u0 = *reinterpret_cast<const ushort4*>(&XB[(size_t)s0 * D + l * 4]);
    float4 f0 = bf4f(u0);
    a0.x += f0.x; a0.y += f0.y; a0.z += f0.z; a0.w += f0.w;
  }
  float sc = 1.f / fmaxf((float)(e1 - e0), 1.f);
  float4 o;
  o.x = (a0.x + a1.x + a2.x + a3.x) * sc;
  o.y = (a0.y + a1.y + a2.y + a3.y) * sc;
  o.z = (a0.z + a1.z + a2.z + a3.z) * sc;
  o.w = (a0.w + a1.w + a2.w + a3.w) * sc;
  *reinterpret_cast<float4*>(&AG[(size_t)g * D + l * 4]) = o;
}

// ---------------- SAGE layer via split-bf16 MFMA ----------------
__global__ __launch_bounds__(256) void k_sage_mfma(const float* __restrict__ XS, const float* __restrict__ AG,
    const unsigned short* __restrict__ BTH, const unsigned short* __restrict__ BTL,
    const float* __restrict__ Bb, const float* __restrict__ GM, const float* __restrict__ BT,
    const float* __restrict__ RM, const float* __restrict__ RV,
    float* __restrict__ H, unsigned short* __restrict__ HB, int n, int donan)
{
  __shared__ unsigned short Ah[64 * 40];
  __shared__ unsigned short Al[64 * 40];
  __shared__ unsigned short Bh[128 * 40];
  __shared__ unsigned short Bl[128 * 40];

  int t  = threadIdx.x;
  int l  = t & 63;
  int wv = t >> 6;          // wave 0..3 -> rows wv*16..+15
  int lm = l & 15;          // frag row (A) / col (B,D)
  int lk = l >> 4;          // k-group 0..3
  int node0 = blockIdx.x * 64;

  f32x4 acc[8];
  #pragma unroll
  for (int f = 0; f < 8; ++f) acc[f] = (f32x4){0.f, 0.f, 0.f, 0.f};

  for (int step = 0; step < 8; ++step){
    int k0 = step * 32;                          // global k in [0,256)
    const float* srcA = (step < 4) ? XS : AG;
    int koff = (step < 4) ? k0 : (k0 - 128);

    __syncthreads();
    // ---- stage A: 64 rows x 32 k fp32 -> hi/lo bf16 ----
    #pragma unroll
    for (int i = 0; i < 2; ++i){
      int c   = t + i * 256;
      int row = c >> 3, c4 = c & 7;
      int node = min(node0 + row, n - 1);
      float4 v = *reinterpret_cast<const float4*>(&srcA[(size_t)node * D + koff + c4 * 4]);
      const float* vp = (const float*)&v;
      unsigned short hh[4], ll[4];
      #pragma unroll
      for (int j = 0; j < 4; ++j){
        unsigned short hi = f2bf_rn(vp[j]);
        hh[j] = hi;
        ll[j] = f2bf_rn(vp[j] - bf2f(hi));
      }
      uint2 wh, wl;
      wh.x = (unsigned)hh[0] | ((unsigned)hh[1] << 16);
      wh.y = (unsigned)hh[2] | ((unsigned)hh[3] << 16);
      wl.x = (unsigned)ll[0] | ((unsigned)ll[1] << 16);
      wl.y = (unsigned)ll[2] | ((unsigned)ll[3] << 16);
      *reinterpret_cast<uint2*>(&Ah[row * 40 + c4 * 4]) = wh;
      *reinterpret_cast<uint2*>(&Al[row * 40 + c4 * 4]) = wl;
    }
    // ---- stage B: 128 cols x 32 k bf16 hi+lo ----
    #pragma unroll
    for (int i = 0; i < 2; ++i){
      int c   = t + i * 256;
      int col = c >> 2, q = c & 3;
      *reinterpret_cast<uint4*>(&Bh[col * 40 + q * 8]) =
          *reinterpret_cast<const uint4*>(&BTH[col * 256 + k0 + q * 8]);
      *reinterpret_cast<uint4*>(&Bl[col * 40 + q * 8]) =
          *reinterpret_cast<const uint4*>(&BTL[col * 256 + k0 + q * 8]);
    }
    __syncthreads();

    // ---- MFMA: 8 col-frags x 3 split terms ----
    bf16x8 afh = *reinterpret_cast<const bf16x8*>(&Ah[(wv * 16 + lm) * 40 + lk * 8]);
    bf16x8 afl = *reinterpret_cast<const bf16x8*>(&Al[(wv * 16 + lm) * 40 + lk * 8]);
    #pragma unroll
    for (int f = 0; f < 8; ++f){
      bf16x8 bfh = *reinterpret_cast<const bf16x8*>(&Bh[(f * 16 + lm) * 40 + lk * 8]);
      bf16x8 bfl = *reinterpret_cast<const bf16x8*>(&Bl[(f * 16 + lm) * 40 + lk * 8]);
      acc[f] = __builtin_amdgcn_mfma_f32_16x16x32_bf16(afh, bfh, acc[f], 0, 0, 0);
      acc[f] = __builtin_amdgcn_mfma_f32_16x16x32_bf16(afl, bfh, acc[f], 0, 0, 0);
      acc[f] = __builtin_amdgcn_mfma_f32_16x16x32_bf16(afh, bfl, acc[f], 0, 0, 0);
    }
  }

  // ---- epilogue: BN + leaky relu (+ nan_to_num layer 2) ----
  #pragma unroll
  for (int f = 0; f < 8; ++f){
    int col = f * 16 + lm;
    float s  = GM[col] * rsqrtf(RV[col] + BN_EPS);
    float cj = (Bb[col] - RM[col]) * s + BT[col];
    #pragma unroll
    for (int r = 0; r < 4; ++r){
      int node = node0 + wv * 16 + lk * 4 + r;
      if (node < n){
        float v = lrelu(acc[f][r] * s + cj);
        if (donan && (v != v)) v = 1e-14f;
        H[(size_t)node * D + col] = v;
        if (HB) HB[(size_t)node * D + col] = f2bf_rn(v);
      }
    }
  }
}

// ---------------- candidate MLP via split-bf16 MFMA ----------------
// 64 candidates/block (1 M-frag per wave), grid 1563 -> ~6 waves/SIMD (the
// round-8 version had 2 M-frags/wave and only 23% occupancy, gather-latency
// bound). L1 k-loop software-pipelined depth 2: step s+1's loads issue
// before step s's split+MFMA.
__global__ __launch_bounds__(256) void k_mlp_mfma(const float* __restrict__ H,
    const int* __restrict__ cu, const int* __restrict__ cv, const float* __restrict__ cf,
    const unsigned short* __restrict__ W0H, const unsigned short* __restrict__ W0L,
    const float* __restrict__ mw0, const float* __restrict__ mb0,
    const unsigned short* __restrict__ W1H, const unsigned short* __restrict__ W1L,
    const float* __restrict__ mb1, const float* __restrict__ mw2, const float* __restrict__ mb2,
    float* __restrict__ y, int C)
{
  __shared__ unsigned short zh[4][16 * 72];   // per-wave z tile, hi (rows 144B)
  __shared__ unsigned short zl[4][16 * 72];   // per-wave z tile, lo

  int t = threadIdx.x;
  int wv = t >> 6, l = t & 63, lm = l & 15, lk = l >> 4;
  int candbase = blockIdx.x * 64 + wv * 16;

  int cc = min(candbase + lm, C - 1);
  const float* rowu = &H[(size_t)cu[cc] * D];
  const float* rowv = &H[(size_t)cv[cc] * D];

  // ---- layer 1: K = 256 via MFMA, depth-2 pipelined gather ----
  f32x4 acc[4];
  #pragma unroll
  for (int f = 0; f < 4; ++f) acc[f] = (f32x4){0.f, 0.f, 0.f, 0.f};

  int kbase = lk * 8;
  float4 curA = *reinterpret_cast<const float4*>(&rowu[kbase]);
  float4 curB = *reinterpret_cast<const float4*>(&rowu[kbase + 4]);

  #pragma unroll
  for (int s = 0; s < 8; ++s){
    float4 nxtA, nxtB;
    if (s < 7){
      const float* rw = (s + 1 < 4) ? rowu : rowv;
      int koff = ((s + 1) & 3) * 32 + kbase;
      nxtA = *reinterpret_cast<const float4*>(&rw[koff]);
      nxtB = *reinterpret_cast<const float4*>(&rw[koff + 4]);
    }
    uint4 hh, ll;
    split8(curA, curB, hh, ll);
    bf16x8 afh = *reinterpret_cast<bf16x8*>(&hh);
    bf16x8 afl = *reinterpret_cast<bf16x8*>(&ll);
    int k0 = s * 32 + kbase;
    #pragma unroll
    for (int f = 0; f < 4; ++f){
      int col = f * 16 + lm;
      bf16x8 bh = *reinterpret_cast<const bf16x8*>(&W0H[(size_t)col * 264 + k0]);
      bf16x8 bl = *reinterpret_cast<const bf16x8*>(&W0L[(size_t)col * 264 + k0]);
      acc[f] = __builtin_amdgcn_mfma_f32_16x16x32_bf16(afh, bh, acc[f], 0, 0, 0);
      acc[f] = __builtin_amdgcn_mfma_f32_16x16x32_bf16(afl, bh, acc[f], 0, 0, 0);
      acc[f] = __builtin_amdgcn_mfma_f32_16x16x32_bf16(afh, bl, acc[f], 0, 0, 0);
    }
    if (s < 7){ curA = nxtA; curB = nxtB; }
  }

  // ---- L1 epilogue: bias + feat term + lrelu, write z hi/lo to LDS ----
  float cfv[4];
  #pragma unroll
  for (int r = 0; r < 4; ++r)
    cfv[r] = cf[min(candbase + lk * 4 + r, C - 1)];

  #pragma unroll
  for (int f = 0; f < 4; ++f){
    int col = f * 16 + lm;
    float b0v = mb0[col];
    float wfv = mw0[256 * 64 + col];
    #pragma unroll
    for (int r = 0; r < 4; ++r){
      int cl = lk * 4 + r;
      float z = lrelu(acc[f][r] + b0v + cfv[r] * wfv);
      unsigned short h16 = f2bf_rn(z);
      zh[wv][cl * 72 + col] = h16;
      zl[wv][cl * 72 + col] = f2bf_rn(z - bf2f(h16));
    }
  }
  // wave-local LDS: hardware lgkmcnt ordering covers write->read, no barrier

  // ---- layer 2: K = 64 via MFMA ----
  f32x4 a2[4];
  #pragma unroll
  for (int f = 0; f < 4; ++f) a2[f] = (f32x4){0.f, 0.f, 0.f, 0.f};

  #pragma unroll
  for (int s2 = 0; s2 < 2; ++s2){
    int kk = s2 * 32 + kbase;
    bf16x8 azh = *reinterpret_cast<const bf16x8*>(&zh[wv][lm * 72 + kk]);
    bf16x8 azl = *reinterpret_cast<const bf16x8*>(&zl[wv][lm * 72 + kk]);
    #pragma unroll
    for (int f = 0; f < 4; ++f){
      int col = f * 16 + lm;
      bf16x8 bh = *reinterpret_cast<const bf16x8*>(&W1H[(size_t)col * 64 + kk]);
      bf16x8 bl = *reinterpret_cast<const bf16x8*>(&W1L[(size_t)col * 64 + kk]);
      a2[f] = __builtin_amdgcn_mfma_f32_16x16x32_bf16(azh, bh, a2[f], 0, 0, 0);
      a2[f] = __builtin_amdgcn_mfma_f32_16x16x32_bf16(azl, bh, a2[f], 0, 0, 0);
      a2[f] = __builtin_amdgcn_mfma_f32_16x16x32_bf16(azh, bl, a2[f], 0, 0, 0);
    }
  }

  // ---- layer 3: 64 -> 1 : per-lane partial + 16-lane xor reduce ----
  float p0 = 0.f, p1 = 0.f, p2 = 0.f, p3 = 0.f;
  #pragma unroll
  for (int f = 0; f < 4; ++f){
    int col = f * 16 + lm;
    float b1v = mb1[col];
    float w2v = mw2[col];
    p0 = fmaf(lrelu(a2[f][0] + b1v), w2v, p0);
    p1 = fmaf(lrelu(a2[f][1] + b1v), w2v, p1);
    p2 = fmaf(lrelu(a2[f][2] + b1v), w2v, p2);
    p3 = fmaf(lrelu(a2[f][3] + b1v), w2v, p3);
  }
  #pragma unroll
  for (int off = 1; off < 16; off <<= 1){
    p0 += __shfl_xor(p0, off); p1 += __shfl_xor(p1, off);
    p2 += __shfl_xor(p2, off); p3 += __shfl_xor(p3, off);
  }
  if (lm == 0){
    float b2 = mb2[0];
    int base0 = candbase + lk * 4;
    if (base0 + 0 < C) y[base0 + 0] = p0 + b2;
    if (base0 + 1 < C) y[base0 + 1] = p1 + b2;
    if (base0 + 2 < C) y[base0 + 2] = p2 + b2;
    if (base0 + 3 < C) y[base0 + 3] = p3 + b2;
  }
}

// ---------------- softmax over C logits ----------------
__global__ __launch_bounds__(256) void k_red1(const float* __restrict__ y,
                                              float* __restrict__ bmax, float* __restrict__ bsum, int C){
  __shared__ float sm[4];
  __shared__ float ss[4];
  int t = threadIdx.x;
  float m = -3.4e38f;
  for (int i = blockIdx.x * 256 + t; i < C; i += gridDim.x * 256) m = fmaxf(m, y[i]);
  for (int o = 32; o; o >>= 1) m = fmaxf(m, __shfl_xor(m, o));
  if ((t & 63) == 0) sm[t >> 6] = m;
  __syncthreads();
  float bm = fmaxf(fmaxf(sm[0], sm[1]), fmaxf(sm[2], sm[3]));
  float s = 0.f;
  for (int i = blockIdx.x * 256 + t; i < C; i += gridDim.x * 256) s += expf(y[i] - bm);
  for (int o = 32; o; o >>= 1) s += __shfl_xor(s, o);
  if ((t & 63) == 0) ss[t >> 6] = s;
  __syncthreads();
  if (t == 0){ bmax[blockIdx.x] = bm; bsum[blockIdx.x] = ss[0] + ss[1] + ss[2] + ss[3]; }
}

__global__ __launch_bounds__(256) void k_red2(const float* __restrict__ bmax, const float* __restrict__ bsum,
                                              float* __restrict__ g, int nb){
  __shared__ float sm[4];
  __shared__ float ss[4];
  int t = threadIdx.x;
  float m0 = (t < nb) ? bmax[t] : -3.4e38f;
  float m = m0;
  for (int o = 32; o; o >>= 1) m = fmaxf(m, __shfl_xor(m, o));
  if ((t & 63) == 0) sm[t >> 6] = m;
  __syncthreads();
  float gm = fmaxf(fmaxf(sm[0], sm[1]), fmaxf(sm[2], sm[3]));
  float s = (t < nb) ? bsum[t] * expf(m0 - gm) : 0.f;
  for (int o = 32; o; o >>= 1) s += __shfl_xor(s, o);
  if ((t & 63) == 0) ss[t >> 6] = s;
  __syncthreads();
  if (t == 0){ g[0] = gm; g[1] = 1.f / (ss[0] + ss[1] + ss[2] + ss[3]); }
}

__global__ __launch_bounds__(256) void k_red3(const float* __restrict__ y, const float* __restrict__ g,
                                              float* __restrict__ out, int C){
  int i = blockIdx.x * 256 + threadIdx.x;
  if (i < C) out[i] = expf(y[i] - g[0]) * g[1];
}

extern "C" void kernel_launch(void* const* d_in, const int* in_sizes, int n_in,
                              void* d_out, int out_size, void* d_ws, size_t ws_size,
                              hipStream_t stream)
{
  const float* x   = (const float*)d_in[0];
  const int*   src = (const int*)  d_in[1];
  const int*   dst = (const int*)  d_in[2];
  const int*   cu  = (const int*)  d_in[3];
  const int*   cv  = (const int*)  d_in[4];
  const float* cf  = (const float*)d_in[5];
  const float* ws0 = (const float*)d_in[6];
  const float* wn0 = (const float*)d_in[7];
  const float* b0  = (const float*)d_in[8];
  const float* g0  = (const float*)d_in[9];
  const float* be0 = (const float*)d_in[10];
  const float* rm0 = (const float*)d_in[11];
  const float* rv0 = (const float*)d_in[12];
  const float* ws1 = (const float*)d_in[13];
  const float* wn1 = (const float*)d_in[14];
  const float* b1  = (const float*)d_in[15];
  const float* g1  = (const float*)d_in[16];
  const float* be1 = (const float*)d_in[17];
  const float* rm1 = (const float*)d_in[18];
  const float* rv1 = (const float*)d_in[19];
  const float* mw0 = (const float*)d_in[20];
  const float* mb0 = (const float*)d_in[21];
  const float* mw1 = (const float*)d_in[22];
  const float* mb1 = (const float*)d_in[23];
  const float* mw2 = (const float*)d_in[24];
  const float* mb2 = (const float*)d_in[25];

  float* out = (float*)d_out;   // [C] y then [C] softmax

  char* w = (char*)d_ws;
  float* aggn  = (float*)w; w += (size_t)N_NODES * D * 4;
  float* h0    = (float*)w; w += (size_t)N_NODES * D * 4;
  float* h1    = (float*)w; w += (size_t)N_NODES * D * 4;
  int* cnt     = (int*)w;   w += (size_t)N_NODES * 4;          // -> SAGE weights L0
  int* rowptr  = (int*)w;   w += (size_t)(N_NODES + 1) * 4;
  int* cur     = (int*)w;   w += (size_t)N_NODES * 4;          // -> SAGE weights L1
  int* eid     = (int*)w;   w += (size_t)N_EDGES * 4;          // holds eid16 (ushort)
  int* gcnt    = (int*)w;   w += (size_t)(NB2 + 8) * 4;
  int* bbase   = (int*)w;   w += (size_t)(NB2 + 1) * 4;
  float* bmax  = (float*)w; w += 256 * 4;
  float* bsumF = (float*)w; w += 256 * 4;
  float* gred  = (float*)w; w += 2 * 4;
  // split MLP weights (transposed): w0 [64][264] hi/lo, w1 [64][64] hi/lo
  unsigned short* w0th = (unsigned short*)w; w += (size_t)64 * 264 * 2;
  unsigned short* w0tl = (unsigned short*)w; w += (size_t)64 * 264 * 2;
  unsigned short* w1th = (unsigned short*)w; w += (size_t)64 * 64 * 2;
  unsigned short* w1tl = (unsigned short*)w; w += (size_t)64 * 64 * 2;

  unsigned short* eid16 = (unsigned short*)eid;

  // edge bins OVERLAY h0 (h0 only live sage0 -> sage1, after CSR build):
  unsigned* ebin = (unsigned*)h0;      // NB2*BCAP*4 = 3.7 MB << 25.6 MB

  // bf16 gather planes OVERLAY the h1 region:
  //   xb  live [cvt_x .. agg0],  hb0 live [sage0 .. agg1],  h1 live [sage1 .. mlp]
  unsigned short* xb  = (unsigned short*)h1;
  unsigned short* hb0 = xb + (size_t)N_NODES * D;

  // split-bf16 SAGE weight buffers alias the cnt/cur scratch:
  unsigned short* bth0 = (unsigned short*)cnt;
  unsigned short* btl0 = bth0 + 128 * 256;
  unsigned short* bth1 = (unsigned short*)cur;
  unsigned short* btl1 = bth1 + 128 * 256;

  // ---- CSR build (tiled LDS binning; writes coalesced by construction) ----
  hipMemsetAsync(gcnt, 0, (size_t)NB2 * 4, stream);
  k_bin   <<<NTILE, 256, 0, stream>>>(src, dst, gcnt, ebin, N_EDGES);
  k_bscan2<<<1, 256, 0, stream>>>(gcnt, bbase, rowptr);
  k_bfin  <<<NB2, 256, 0, stream>>>(gcnt, bbase, ebin, eid16, rowptr, N_NODES);

  // ---- weight conversions (independent) ----
  k_cvt_w<<<128, 256, 0, stream>>>(ws0, wn0, bth0, btl0);
  k_cvt_w<<<128, 256, 0, stream>>>(ws1, wn1, bth1, btl1);
  k_cvt_mlp<<<64, 256, 0, stream>>>(mw0, 257, 264, w0th, w0tl);
  k_cvt_mlp<<<64, 256, 0, stream>>>(mw1, 64, 64, w1th, w1tl);
  k_cvt_x<<<(N_NODES * D / 4 + 255) / 256, 256, 0, stream>>>(x, xb, N_NODES * D / 4);

  int GB = (N_NODES + 63) / 64;     // 782
  k_agg_bf<<<(N_NODES + 7) / 8, 256, 0, stream>>>(xb, rowptr, eid16, aggn, N_NODES);
  k_sage_mfma<<<GB, 256, 0, stream>>>(x,  aggn, bth0, btl0, b0, g0, be0, rm0, rv0, h0, hb0, N_NODES, 0);
  k_agg_bf<<<(N_NODES + 7) / 8, 256, 0, stream>>>(hb0, rowptr, eid16, aggn, N_NODES);
  k_sage_mfma<<<GB, 256, 0, stream>>>(h0, aggn, bth1, btl1, b1, g1, be1, rm1, rv1, h1, (unsigned short*)0, N_NODES, 1);

  k_mlp_mfma<<<(N_CAND + 63) / 64, 256, 0, stream>>>(h1, cu, cv, cf,
      w0th, w0tl, mw0, mb0, w1th, w1tl, mb1, mw2, mb2, out, N_CAND);

  k_red1<<<256, 256, 0, stream>>>(out, bmax, bsumF, N_CAND);
  k_red2<<<1, 256, 0, stream>>>(bmax, bsumF, gred, 256);
  k_red3<<<(N_CAND + 255) / 256, 256, 0, stream>>>(out, gred, out + N_CAND, N_CAND);
}

// Round 10
// 230.221 us; speedup vs baseline: 1.0437x; 1.0437x over previous
//
#include <hip/hip_runtime.h>
#include <math.h>

#define N_NODES 50000
#define N_EDGES 800000
#define N_CAND  100000
#define D       128
#define BN_EPS  1e-5f
#define SLOPE   0.01f

// tiled-binning CSR build
#define NB2     196      // coarse buckets of 256 nodes (d >> 8), covers 50176
#define TILE    4096     // edges per k_bin block
#define NTILE   196      // 196 * 4096 = 802816 >= E
#define BCAP    4736     // per-bucket capacity: mean 4096, +10 sigma

typedef __attribute__((ext_vector_type(8))) short bf16x8;
typedef __attribute__((ext_vector_type(4))) float f32x4;

__device__ __forceinline__ float lrelu(float x){ return x >= 0.f ? x : SLOPE * x; }

__device__ __forceinline__ unsigned short f2bf_rn(float f){
  unsigned int u = __float_as_uint(f);
  unsigned int r = u + 0x7FFFu + ((u >> 16) & 1u);
  return (unsigned short)(r >> 16);
}
__device__ __forceinline__ float bf2f(unsigned short h){
  return __uint_as_float(((unsigned int)h) << 16);
}
__device__ __forceinline__ float4 bf4f(ushort4 u){
  return make_float4(__uint_as_float((unsigned)u.x << 16),
                     __uint_as_float((unsigned)u.y << 16),
                     __uint_as_float((unsigned)u.z << 16),
                     __uint_as_float((unsigned)u.w << 16));
}

// ---------------- CSR build: LDS-staged tiled binning ----------------
__global__ __launch_bounds__(256) void k_bin(const int* __restrict__ src, const int* __restrict__ dst,
                                             int* __restrict__ gcnt, unsigned* __restrict__ ebin, int E){
  __shared__ unsigned stage[TILE];
  __shared__ int hist[256], lscan[256], lex[256], lcur[256], gbase[256];
  __shared__ int stot;
  int t = threadIdx.x;
  int e0 = blockIdx.x * TILE;

  hist[t] = 0;
  __syncthreads();

  unsigned pk[16]; int bk[16]; bool ok[16];
  #pragma unroll
  for (int j = 0; j < 16; ++j){
    int i = e0 + j * 256 + t;
    ok[j] = (i < E);
    if (ok[j]){
      int d = dst[i];
      pk[j] = ((unsigned)d << 16) | (unsigned)src[i];
      bk[j] = d >> 8;
      atomicAdd(&hist[bk[j]], 1);
    }
  }
  __syncthreads();

  lscan[t] = hist[t];
  __syncthreads();
  for (int off = 1; off < 256; off <<= 1){
    int v = (t >= off) ? lscan[t - off] : 0;
    __syncthreads();
    lscan[t] += v;
    __syncthreads();
  }
  int ex = lscan[t] - hist[t];
  lex[t]  = ex;
  lcur[t] = ex;
  if (t < NB2) gbase[t] = hist[t] ? atomicAdd(&gcnt[t], hist[t]) : 0;
  if (t == 255) stot = lscan[255];
  __syncthreads();

  #pragma unroll
  for (int j = 0; j < 16; ++j){
    if (ok[j]){
      int p = atomicAdd(&lcur[bk[j]], 1);
      stage[p] = pk[j];
    }
  }
  __syncthreads();

  int tot = stot;
  for (int i = t; i < tot; i += 256){
    unsigned e = stage[i];
    int b = (int)(e >> 24);
    ebin[(size_t)b * BCAP + gbase[b] + (i - lex[b])] = e;
  }
}

__global__ __launch_bounds__(256) void k_bscan2(const int* __restrict__ gcnt, int* __restrict__ bbase,
                                                int* __restrict__ rowptr){
  __shared__ int sd[256];
  int t = threadIdx.x;
  int v = (t < NB2) ? gcnt[t] : 0;
  sd[t] = v; __syncthreads();
  for (int off = 1; off < 256; off <<= 1){
    int a = (t >= off) ? sd[t - off] : 0;
    __syncthreads();
    sd[t] += a; __syncthreads();
  }
  if (t < NB2) bbase[t] = sd[t] - v;
  if (t == NB2 - 1) rowptr[N_NODES] = sd[t];
}

__global__ __launch_bounds__(256) void k_bfin(const int* __restrict__ gcnt, const int* __restrict__ bbase,
                                              const unsigned* __restrict__ ebin,
                                              unsigned short* __restrict__ eid16,
                                              int* __restrict__ rowptr, int n){
  __shared__ int hist[256], lb[256], lcur[256];
  int t = threadIdx.x, b = blockIdx.x;
  int cb   = gcnt[b];
  int base = bbase[b];
  const unsigned* eb = &ebin[(size_t)b * BCAP];
  hist[t] = 0;
  __syncthreads();
  for (int idx = t; idx < cb; idx += 256) atomicAdd(&hist[(eb[idx] >> 16) & 255], 1);
  __syncthreads();
  lb[t] = hist[t];
  __syncthreads();
  for (int off = 1; off < 256; off <<= 1){
    int v = (t >= off) ? lb[t - off] : 0;
    __syncthreads();
    lb[t] += v; __syncthreads();
  }
  int ex = lb[t] - hist[t];
  lcur[t] = ex;
  int node = (b << 8) + t;
  if (node < n) rowptr[node] = base + ex;
  __syncthreads();
  for (int idx = t; idx < cb; idx += 256){
    unsigned e = eb[idx];
    int p = atomicAdd(&lcur[(e >> 16) & 255], 1);
    eid16[base + p] = (unsigned short)(e & 0xffffu);
  }
}

// ---------------- weight transpose + bf16 hi/lo split (SAGE) ----------------
__global__ __launch_bounds__(256) void k_cvt_w(const float* __restrict__ ws, const float* __restrict__ wn,
                                               unsigned short* __restrict__ bth, unsigned short* __restrict__ btl){
  int col = blockIdx.x;       // 0..127
  int k   = threadIdx.x;      // 0..255
  float v = (k < 128) ? ws[k * D + col] : wn[(k - 128) * D + col];
  unsigned short hi = f2bf_rn(v);
  unsigned short lo = f2bf_rn(v - bf2f(hi));
  bth[col * 256 + k] = hi;
  btl[col * 256 + k] = lo;
}

// ---------------- MLP weight transpose + split: w[K x 64] -> T_h/T_l [64][Kpad] ----------------
__global__ __launch_bounds__(256) void k_cvt_mlp(const float* __restrict__ w, int K, int Kpad,
                                                 unsigned short* __restrict__ th, unsigned short* __restrict__ tl){
  int col = blockIdx.x;       // 0..63
  for (int k = threadIdx.x; k < Kpad; k += 256){
    float v = (k < K) ? w[k * 64 + col] : 0.f;
    unsigned short hi = f2bf_rn(v);
    th[col * Kpad + k] = hi;
    tl[col * Kpad + k] = f2bf_rn(v - bf2f(hi));
  }
}

// ---------------- x -> bf16 plane ----------------
__global__ __launch_bounds__(256) void k_cvt_x(const float* __restrict__ X, unsigned short* __restrict__ XB, int nel4){
  int i = blockIdx.x * 256 + threadIdx.x;
  if (i < nel4){
    float4 v = *reinterpret_cast<const float4*>(&X[(size_t)i * 4]);
    ushort4 u;
    u.x = f2bf_rn(v.x); u.y = f2bf_rn(v.y); u.z = f2bf_rn(v.z); u.w = f2bf_rn(v.w);
    *reinterpret_cast<ushort4*>(&XB[(size_t)i * 4]) = u;
  }
}

// ---------------- mean aggregation: bf16 gather, fp32 accumulate ----------------
__global__ __launch_bounds__(256) void k_agg_bf(const unsigned short* __restrict__ XB,
                                                const int* __restrict__ rowptr, const unsigned short* __restrict__ eid,
                                                float* __restrict__ AG, int n){
  int g = blockIdx.x * 8 + (threadIdx.x >> 5);   // node
  int l = threadIdx.x & 31;                      // 4-bf16 chunk
  if (g >= n) return;
  int e0 = rowptr[g], e1 = rowptr[g + 1];
  float4 a0 = make_float4(0.f,0.f,0.f,0.f);
  float4 a1 = make_float4(0.f,0.f,0.f,0.f);
  float4 a2 = make_float4(0.f,0.f,0.f,0.f);
  float4 a3 = make_float4(0.f,0.f,0.f,0.f);
  int e = e0;
  for (; e + 4 <= e1; e += 4){
    int s0 = eid[e], s1 = eid[e + 1], s2 = eid[e + 2], s3 = eid[e + 3];
    ushort4 u0 = *reinterpret_cast<const ushort4*>(&XB[(size_t)s0 * D + l * 4]);
    ushort4 u1 = *reinterpret_cast<const ushort4*>(&XB[(size_t)s1 * D + l * 4]);
    ushort4 u2 = *reinterpret_cast<const ushort4*>(&XB[(size_t)s2 * D + l * 4]);
    ushort4 u3 = *reinterpret_cast<const ushort4*>(&XB[(size_t)s3 * D + l * 4]);
    float4 f0 = bf4f(u0), f1 = bf4f(u1), f2 = bf4f(u2), f3 = bf4f(u3);
    a0.x += f0.x; a0.y += f0.y; a0.z += f0.z; a0.w += f0.w;
    a1.x += f1.x; a1.y += f1.y; a1.z += f1.z; a1.w += f1.w;
    a2.x += f2.x; a2.y += f2.y; a2.z += f2.z; a2.w += f2.w;
    a3.x += f3.x; a3.y += f3.y; a3.z += f3.z; a3.w += f3.w;
  }
  for (; e < e1; ++e){
    int s0 = eid[e];
    ushort4 u0 = *reinterpret_cast<const ushort4*>(&XB[(size_t)s0 * D + l * 4]);
    float4 f0 = bf4f(u0);
    a0.x += f0.x; a0.y += f0.y; a0.z += f0.z; a0.w += f0.w;
  }
  float sc = 1.f / fmaxf((float)(e1 - e0), 1.f);
  float4 o;
  o.x = (a0.x + a1.x + a2.x + a3.x) * sc;
  o.y = (a0.y + a1.y + a2.y + a3.y) * sc;
  o.z = (a0.z + a1.z + a2.z + a3.z) * sc;
  o.w = (a0.w + a1.w + a2.w + a3.w) * sc;
  *reinterpret_cast<float4*>(&AG[(size_t)g * D + l * 4]) = o;
}

// ---------------- SAGE layer via split-bf16 MFMA ----------------
// Outputs are optional: H (fp32), HBH (bf16 hi plane), HBL (bf16 lo plane).
// Layer 0 writes H=h0 + HBH=hb0 (agg gather). Layer 1 writes ONLY pre-split
// HBH/HBL planes: the MLP consumes h1 exclusively as split-bf16 A-fragments,
// so splitting once at the producer removes the per-consumer split8 VALU
// chain from k_mlp's gather critical path (numerically identical values).
__global__ __launch_bounds__(256) void k_sage_mfma(const float* __restrict__ XS, const float* __restrict__ AG,
    const unsigned short* __restrict__ BTH, const unsigned short* __restrict__ BTL,
    const float* __restrict__ Bb, const float* __restrict__ GM, const float* __restrict__ BT,
    const float* __restrict__ RM, const float* __restrict__ RV,
    float* __restrict__ H, unsigned short* __restrict__ HBH, unsigned short* __restrict__ HBL,
    int n, int donan)
{
  __shared__ unsigned short Ah[64 * 40];
  __shared__ unsigned short Al[64 * 40];
  __shared__ unsigned short Bh[128 * 40];
  __shared__ unsigned short Bl[128 * 40];

  int t  = threadIdx.x;
  int l  = t & 63;
  int wv = t >> 6;          // wave 0..3 -> rows wv*16..+15
  int lm = l & 15;          // frag row (A) / col (B,D)
  int lk = l >> 4;          // k-group 0..3
  int node0 = blockIdx.x * 64;

  f32x4 acc[8];
  #pragma unroll
  for (int f = 0; f < 8; ++f) acc[f] = (f32x4){0.f, 0.f, 0.f, 0.f};

  for (int step = 0; step < 8; ++step){
    int k0 = step * 32;                          // global k in [0,256)
    const float* srcA = (step < 4) ? XS : AG;
    int koff = (step < 4) ? k0 : (k0 - 128);

    __syncthreads();
    // ---- stage A: 64 rows x 32 k fp32 -> hi/lo bf16 ----
    #pragma unroll
    for (int i = 0; i < 2; ++i){
      int c   = t + i * 256;
      int row = c >> 3, c4 = c & 7;
      int node = min(node0 + row, n - 1);
      float4 v = *reinterpret_cast<const float4*>(&srcA[(size_t)node * D + koff + c4 * 4]);
      const float* vp = (const float*)&v;
      unsigned short hh[4], ll[4];
      #pragma unroll
      for (int j = 0; j < 4; ++j){
        unsigned short hi = f2bf_rn(vp[j]);
        hh[j] = hi;
        ll[j] = f2bf_rn(vp[j] - bf2f(hi));
      }
      uint2 wh, wl;
      wh.x = (unsigned)hh[0] | ((unsigned)hh[1] << 16);
      wh.y = (unsigned)hh[2] | ((unsigned)hh[3] << 16);
      wl.x = (unsigned)ll[0] | ((unsigned)ll[1] << 16);
      wl.y = (unsigned)ll[2] | ((unsigned)ll[3] << 16);
      *reinterpret_cast<uint2*>(&Ah[row * 40 + c4 * 4]) = wh;
      *reinterpret_cast<uint2*>(&Al[row * 40 + c4 * 4]) = wl;
    }
    // ---- stage B: 128 cols x 32 k bf16 hi+lo ----
    #pragma unroll
    for (int i = 0; i < 2; ++i){
      int c   = t + i * 256;
      int col = c >> 2, q = c & 3;
      *reinterpret_cast<uint4*>(&Bh[col * 40 + q * 8]) =
          *reinterpret_cast<const uint4*>(&BTH[col * 256 + k0 + q * 8]);
      *reinterpret_cast<uint4*>(&Bl[col * 40 + q * 8]) =
          *reinterpret_cast<const uint4*>(&BTL[col * 256 + k0 + q * 8]);
    }
    __syncthreads();

    // ---- MFMA: 8 col-frags x 3 split terms ----
    bf16x8 afh = *reinterpret_cast<const bf16x8*>(&Ah[(wv * 16 + lm) * 40 + lk * 8]);
    bf16x8 afl = *reinterpret_cast<const bf16x8*>(&Al[(wv * 16 + lm) * 40 + lk * 8]);
    #pragma unroll
    for (int f = 0; f < 8; ++f){
      bf16x8 bfh = *reinterpret_cast<const bf16x8*>(&Bh[(f * 16 + lm) * 40 + lk * 8]);
      bf16x8 bfl = *reinterpret_cast<const bf16x8*>(&Bl[(f * 16 + lm) * 40 + lk * 8]);
      acc[f] = __builtin_amdgcn_mfma_f32_16x16x32_bf16(afh, bfh, acc[f], 0, 0, 0);
      acc[f] = __builtin_amdgcn_mfma_f32_16x16x32_bf16(afl, bfh, acc[f], 0, 0, 0);
      acc[f] = __builtin_amdgcn_mfma_f32_16x16x32_bf16(afh, bfl, acc[f], 0, 0, 0);
    }
  }

  // ---- epilogue: BN + leaky relu (+ nan_to_num layer 2) ----
  #pragma unroll
  for (int f = 0; f < 8; ++f){
    int col = f * 16 + lm;
    float s  = GM[col] * rsqrtf(RV[col] + BN_EPS);
    float cj = (Bb[col] - RM[col]) * s + BT[col];
    #pragma unroll
    for (int r = 0; r < 4; ++r){
      int node = node0 + wv * 16 + lk * 4 + r;
      if (node < n){
        float v = lrelu(acc[f][r] * s + cj);
        if (donan && (v != v)) v = 1e-14f;
        if (H)  H[(size_t)node * D + col] = v;
        unsigned short h16 = f2bf_rn(v);
        if (HBH) HBH[(size_t)node * D + col] = h16;
        if (HBL) HBL[(size_t)node * D + col] = f2bf_rn(v - bf2f(h16));
      }
    }
  }
}

// ---------------- candidate MLP via split-bf16 MFMA ----------------
// Round-8 structure (128 cands/block, 2 M-frags/wave = 4 gather streams in
// flight; round-9's 1-M-frag variant HALVED per-wave MLP and regressed
// 42->57us). A-fragments load DIRECTLY from pre-split bf16 planes (HH/HL)
// -> no split8 VALU on the critical path; depth-2 prefetch: step s+1's four
// 16B loads issue before step s's 24 MFMAs.
__global__ __launch_bounds__(256) void k_mlp_mfma(
    const unsigned short* __restrict__ HH, const unsigned short* __restrict__ HL,
    const int* __restrict__ cu, const int* __restrict__ cv, const float* __restrict__ cf,
    const unsigned short* __restrict__ W0H, const unsigned short* __restrict__ W0L,
    const float* __restrict__ mw0, const float* __restrict__ mb0,
    const unsigned short* __restrict__ W1H, const unsigned short* __restrict__ W1L,
    const float* __restrict__ mb1, const float* __restrict__ mw2, const float* __restrict__ mb2,
    float* __restrict__ y, int C)
{
  __shared__ unsigned short zh[4][32 * 72];   // per-wave z tile, hi (rows 144B)
  __shared__ unsigned short zl[4][32 * 72];   // per-wave z tile, lo

  int t = threadIdx.x;
  int wv = t >> 6, l = t & 63, lm = l & 15, lk = l >> 4;
  int candbase = blockIdx.x * 128 + wv * 32;

  int c0 = min(candbase + lm,      C - 1);
  int c1 = min(candbase + 16 + lm, C - 1);
  int nu0 = cu[c0], nv0 = cv[c0];
  int nu1 = cu[c1], nv1 = cv[c1];

  // ---- layer 1: K = 256 via MFMA, depth-2 pipelined pre-split gather ----
  f32x4 acc[2][4];
  #pragma unroll
  for (int m = 0; m < 2; ++m)
    #pragma unroll
    for (int f = 0; f < 4; ++f) acc[m][f] = (f32x4){0.f, 0.f, 0.f, 0.f};

  int kbase = lk * 8;
  bf16x8 ah0 = *reinterpret_cast<const bf16x8*>(&HH[(size_t)nu0 * D + kbase]);
  bf16x8 al0 = *reinterpret_cast<const bf16x8*>(&HL[(size_t)nu0 * D + kbase]);
  bf16x8 ah1 = *reinterpret_cast<const bf16x8*>(&HH[(size_t)nu1 * D + kbase]);
  bf16x8 al1 = *reinterpret_cast<const bf16x8*>(&HL[(size_t)nu1 * D + kbase]);

  #pragma unroll
  for (int s = 0; s < 8; ++s){
    bf16x8 nh0, nl0, nh1, nl1;
    if (s < 7){
      int n0 = (s + 1 < 4) ? nu0 : nv0;
      int n1 = (s + 1 < 4) ? nu1 : nv1;
      int koff = ((s + 1) & 3) * 32 + kbase;
      nh0 = *reinterpret_cast<const bf16x8*>(&HH[(size_t)n0 * D + koff]);
      nl0 = *reinterpret_cast<const bf16x8*>(&HL[(size_t)n0 * D + koff]);
      nh1 = *reinterpret_cast<const bf16x8*>(&HH[(size_t)n1 * D + koff]);
      nl1 = *reinterpret_cast<const bf16x8*>(&HL[(size_t)n1 * D + koff]);
    }
    int k0 = s * 32 + kbase;
    #pragma unroll
    for (int f = 0; f < 4; ++f){
      int col = f * 16 + lm;
      bf16x8 bh = *reinterpret_cast<const bf16x8*>(&W0H[(size_t)col * 264 + k0]);
      bf16x8 bl = *reinterpret_cast<const bf16x8*>(&W0L[(size_t)col * 264 + k0]);
      acc[0][f] = __builtin_amdgcn_mfma_f32_16x16x32_bf16(ah0, bh, acc[0][f], 0, 0, 0);
      acc[0][f] = __builtin_amdgcn_mfma_f32_16x16x32_bf16(al0, bh, acc[0][f], 0, 0, 0);
      acc[0][f] = __builtin_amdgcn_mfma_f32_16x16x32_bf16(ah0, bl, acc[0][f], 0, 0, 0);
      acc[1][f] = __builtin_amdgcn_mfma_f32_16x16x32_bf16(ah1, bh, acc[1][f], 0, 0, 0);
      acc[1][f] = __builtin_amdgcn_mfma_f32_16x16x32_bf16(al1, bh, acc[1][f], 0, 0, 0);
      acc[1][f] = __builtin_amdgcn_mfma_f32_16x16x32_bf16(ah1, bl, acc[1][f], 0, 0, 0);
    }
    if (s < 7){ ah0 = nh0; al0 = nl0; ah1 = nh1; al1 = nl1; }
  }

  // ---- L1 epilogue: bias + feat term + lrelu, write z hi/lo to LDS ----
  float cfv[2][4];
  #pragma unroll
  for (int m = 0; m < 2; ++m)
    #pragma unroll
    for (int r = 0; r < 4; ++r)
      cfv[m][r] = cf[min(candbase + m * 16 + lk * 4 + r, C - 1)];

  #pragma unroll
  for (int f = 0; f < 4; ++f){
    int col = f * 16 + lm;
    float b0v = mb0[col];
    float wfv = mw0[256 * 64 + col];
    #pragma unroll
    for (int m = 0; m < 2; ++m){
      #pragma unroll
      for (int r = 0; r < 4; ++r){
        int cl = m * 16 + lk * 4 + r;
        float z = lrelu(acc[m][f][r] + b0v + cfv[m][r] * wfv);
        unsigned short h16 = f2bf_rn(z);
        zh[wv][cl * 72 + col] = h16;
        zl[wv][cl * 72 + col] = f2bf_rn(z - bf2f(h16));
      }
    }
  }
  // wave-local LDS: hardware lgkmcnt ordering covers write->read, no barrier

  // ---- layer 2: K = 64 via MFMA ----
  f32x4 a2[2][4];
  #pragma unroll
  for (int m = 0; m < 2; ++m)
    #pragma unroll
    for (int f = 0; f < 4; ++f) a2[m][f] = (f32x4){0.f, 0.f, 0.f, 0.f};

  #pragma unroll
  for (int s2 = 0; s2 < 2; ++s2){
    int kk = s2 * 32 + kbase;
    bf16x8 azh0 = *reinterpret_cast<const bf16x8*>(&zh[wv][(0 * 16 + lm) * 72 + kk]);
    bf16x8 azl0 = *reinterpret_cast<const bf16x8*>(&zl[wv][(0 * 16 + lm) * 72 + kk]);
    bf16x8 azh1 = *reinterpret_cast<const bf16x8*>(&zh[wv][(1 * 16 + lm) * 72 + kk]);
    bf16x8 azl1 = *reinterpret_cast<const bf16x8*>(&zl[wv][(1 * 16 + lm) * 72 + kk]);
    #pragma unroll
    for (int f = 0; f < 4; ++f){
      int col = f * 16 + lm;
      bf16x8 bh = *reinterpret_cast<const bf16x8*>(&W1H[(size_t)col * 64 + kk]);
      bf16x8 bl = *reinterpret_cast<const bf16x8*>(&W1L[(size_t)col * 64 + kk]);
      a2[0][f] = __builtin_amdgcn_mfma_f32_16x16x32_bf16(azh0, bh, a2[0][f], 0, 0, 0);
      a2[0][f] = __builtin_amdgcn_mfma_f32_16x16x32_bf16(azl0, bh, a2[0][f], 0, 0, 0);
      a2[0][f] = __builtin_amdgcn_mfma_f32_16x16x32_bf16(azh0, bl, a2[0][f], 0, 0, 0);
      a2[1][f] = __builtin_amdgcn_mfma_f32_16x16x32_bf16(azh1, bh, a2[1][f], 0, 0, 0);
      a2[1][f] = __builtin_amdgcn_mfma_f32_16x16x32_bf16(azl1, bh, a2[1][f], 0, 0, 0);
      a2[1][f] = __builtin_amdgcn_mfma_f32_16x16x32_bf16(azh1, bl, a2[1][f], 0, 0, 0);
    }
  }

  // ---- layer 3: 64 -> 1 : per-lane partial + 16-lane xor reduce ----
  float p00 = 0.f, p01 = 0.f, p02 = 0.f, p03 = 0.f;
  float p10 = 0.f, p11 = 0.f, p12 = 0.f, p13 = 0.f;
  #pragma unroll
  for (int f = 0; f < 4; ++f){
    int col = f * 16 + lm;
    float b1v = mb1[col];
    float w2v = mw2[col];
    p00 = fmaf(lrelu(a2[0][f][0] + b1v), w2v, p00);
    p01 = fmaf(lrelu(a2[0][f][1] + b1v), w2v, p01);
    p02 = fmaf(lrelu(a2[0][f][2] + b1v), w2v, p02);
    p03 = fmaf(lrelu(a2[0][f][3] + b1v), w2v, p03);
    p10 = fmaf(lrelu(a2[1][f][0] + b1v), w2v, p10);
    p11 = fmaf(lrelu(a2[1][f][1] + b1v), w2v, p11);
    p12 = fmaf(lrelu(a2[1][f][2] + b1v), w2v, p12);
    p13 = fmaf(lrelu(a2[1][f][3] + b1v), w2v, p13);
  }
  #pragma unroll
  for (int off = 1; off < 16; off <<= 1){
    p00 += __shfl_xor(p00, off); p01 += __shfl_xor(p01, off);
    p02 += __shfl_xor(p02, off); p03 += __shfl_xor(p03, off);
    p10 += __shfl_xor(p10, off); p11 += __shfl_xor(p11, off);
    p12 += __shfl_xor(p12, off); p13 += __shfl_xor(p13, off);
  }
  if (lm == 0){
    float b2 = mb2[0];
    int base0 = candbase + lk * 4;
    int base1 = candbase + 16 + lk * 4;
    if (base0 + 0 < C) y[base0 + 0] = p00 + b2;
    if (base0 + 1 < C) y[base0 + 1] = p01 + b2;
    if (base0 + 2 < C) y[base0 + 2] = p02 + b2;
    if (base0 + 3 < C) y[base0 + 3] = p03 + b2;
    if (base1 + 0 < C) y[base1 + 0] = p10 + b2;
    if (base1 + 1 < C) y[base1 + 1] = p11 + b2;
    if (base1 + 2 < C) y[base1 + 2] = p12 + b2;
    if (base1 + 3 < C) y[base1 + 3] = p13 + b2;
  }
}

// ---------------- softmax over C logits ----------------
__global__ __launch_bounds__(256) void k_red1(const float* __restrict__ y,
                                              float* __restrict__ bmax, float* __restrict__ bsum, int C){
  __shared__ float sm[4];
  __shared__ float ss[4];
  int t = threadIdx.x;
  float m = -3.4e38f;
  for (int i = blockIdx.x * 256 + t; i < C; i += gridDim.x * 256) m = fmaxf(m, y[i]);
  for (int o = 32; o; o >>= 1) m = fmaxf(m, __shfl_xor(m, o));
  if ((t & 63) == 0) sm[t >> 6] = m;
  __syncthreads();
  float bm = fmaxf(fmaxf(sm[0], sm[1]), fmaxf(sm[2], sm[3]));
  float s = 0.f;
  for (int i = blockIdx.x * 256 + t; i < C; i += gridDim.x * 256) s += expf(y[i] - bm);
  for (int o = 32; o; o >>= 1) s += __shfl_xor(s, o);
  if ((t & 63) == 0) ss[t >> 6] = s;
  __syncthreads();
  if (t == 0){ bmax[blockIdx.x] = bm; bsum[blockIdx.x] = ss[0] + ss[1] + ss[2] + ss[3]; }
}

__global__ __launch_bounds__(256) void k_red2(const float* __restrict__ bmax, const float* __restrict__ bsum,
                                              float* __restrict__ g, int nb){
  __shared__ float sm[4];
  __shared__ float ss[4];
  int t = threadIdx.x;
  float m0 = (t < nb) ? bmax[t] : -3.4e38f;
  float m = m0;
  for (int o = 32; o; o >>= 1) m = fmaxf(m, __shfl_xor(m, o));
  if ((t & 63) == 0) sm[t >> 6] = m;
  __syncthreads();
  float gm = fmaxf(fmaxf(sm[0], sm[1]), fmaxf(sm[2], sm[3]));
  float s = (t < nb) ? bsum[t] * expf(m0 - gm) : 0.f;
  for (int o = 32; o; o >>= 1) s += __shfl_xor(s, o);
  if ((t & 63) == 0) ss[t >> 6] = s;
  __syncthreads();
  if (t == 0){ g[0] = gm; g[1] = 1.f / (ss[0] + ss[1] + ss[2] + ss[3]); }
}

__global__ __launch_bounds__(256) void k_red3(const float* __restrict__ y, const float* __restrict__ g,
                                              float* __restrict__ out, int C){
  int i = blockIdx.x * 256 + threadIdx.x;
  if (i < C) out[i] = expf(y[i] - g[0]) * g[1];
}

extern "C" void kernel_launch(void* const* d_in, const int* in_sizes, int n_in,
                              void* d_out, int out_size, void* d_ws, size_t ws_size,
                              hipStream_t stream)
{
  const float* x   = (const float*)d_in[0];
  const int*   src = (const int*)  d_in[1];
  const int*   dst = (const int*)  d_in[2];
  const int*   cu  = (const int*)  d_in[3];
  const int*   cv  = (const int*)  d_in[4];
  const float* cf  = (const float*)d_in[5];
  const float* ws0 = (const float*)d_in[6];
  const float* wn0 = (const float*)d_in[7];
  const float* b0  = (const float*)d_in[8];
  const float* g0  = (const float*)d_in[9];
  const float* be0 = (const float*)d_in[10];
  const float* rm0 = (const float*)d_in[11];
  const float* rv0 = (const float*)d_in[12];
  const float* ws1 = (const float*)d_in[13];
  const float* wn1 = (const float*)d_in[14];
  const float* b1  = (const float*)d_in[15];
  const float* g1  = (const float*)d_in[16];
  const float* be1 = (const float*)d_in[17];
  const float* rm1 = (const float*)d_in[18];
  const float* rv1 = (const float*)d_in[19];
  const float* mw0 = (const float*)d_in[20];
  const float* mb0 = (const float*)d_in[21];
  const float* mw1 = (const float*)d_in[22];
  const float* mb1 = (const float*)d_in[23];
  const float* mw2 = (const float*)d_in[24];
  const float* mb2 = (const float*)d_in[25];

  float* out = (float*)d_out;   // [C] y then [C] softmax

  char* w = (char*)d_ws;
  float* aggn  = (float*)w; w += (size_t)N_NODES * D * 4;
  float* h0    = (float*)w; w += (size_t)N_NODES * D * 4;
  float* h1    = (float*)w; w += (size_t)N_NODES * D * 4;
  int* cnt     = (int*)w;   w += (size_t)N_NODES * 4;          // -> SAGE weights L0
  int* rowptr  = (int*)w;   w += (size_t)(N_NODES + 1) * 4;
  int* cur     = (int*)w;   w += (size_t)N_NODES * 4;          // -> SAGE weights L1
  int* eid     = (int*)w;   w += (size_t)N_EDGES * 4;          // holds eid16 (ushort)
  int* gcnt    = (int*)w;   w += (size_t)(NB2 + 8) * 4;
  int* bbase   = (int*)w;   w += (size_t)(NB2 + 1) * 4;
  float* bmax  = (float*)w; w += 256 * 4;
  float* bsumF = (float*)w; w += 256 * 4;
  float* gred  = (float*)w; w += 2 * 4;
  // split MLP weights (transposed): w0 [64][264] hi/lo, w1 [64][64] hi/lo
  unsigned short* w0th = (unsigned short*)w; w += (size_t)64 * 264 * 2;
  unsigned short* w0tl = (unsigned short*)w; w += (size_t)64 * 264 * 2;
  unsigned short* w1th = (unsigned short*)w; w += (size_t)64 * 64 * 2;
  unsigned short* w1tl = (unsigned short*)w; w += (size_t)64 * 64 * 2;

  unsigned short* eid16 = (unsigned short*)eid;

  // edge bins OVERLAY h0 (h0 only live sage0 -> sage1, after CSR build):
  unsigned* ebin = (unsigned*)h0;      // NB2*BCAP*4 = 3.7 MB << 25.6 MB

  // h1 region timeline (no fp32 h1 is ever written now):
  //   [cvt_x .. agg0]   : xb   (bf16 x plane)       @ h1[0      .. 12.8MB)
  //   [sage0 .. agg1]   : hb0  (bf16 h0 plane)      @ h1[12.8MB .. 25.6MB)
  //   [sage1 .. mlp ]   : hb1h @ h1[0..12.8MB), hb1l @ h1[12.8..25.6MB)
  //   (xb dead before sage1 writes hb1h; hb0 dead after agg1, sage1 runs after)
  unsigned short* xb   = (unsigned short*)h1;
  unsigned short* hb0  = xb + (size_t)N_NODES * D;
  unsigned short* hb1h = (unsigned short*)h1;
  unsigned short* hb1l = hb1h + (size_t)N_NODES * D;

  // split-bf16 SAGE weight buffers alias the cnt/cur scratch:
  unsigned short* bth0 = (unsigned short*)cnt;
  unsigned short* btl0 = bth0 + 128 * 256;
  unsigned short* bth1 = (unsigned short*)cur;
  unsigned short* btl1 = bth1 + 128 * 256;

  // ---- CSR build (tiled LDS binning; writes coalesced by construction) ----
  hipMemsetAsync(gcnt, 0, (size_t)NB2 * 4, stream);
  k_bin   <<<NTILE, 256, 0, stream>>>(src, dst, gcnt, ebin, N_EDGES);
  k_bscan2<<<1, 256, 0, stream>>>(gcnt, bbase, rowptr);
  k_bfin  <<<NB2, 256, 0, stream>>>(gcnt, bbase, ebin, eid16, rowptr, N_NODES);

  // ---- weight conversions (independent) ----
  k_cvt_w<<<128, 256, 0, stream>>>(ws0, wn0, bth0, btl0);
  k_cvt_w<<<128, 256, 0, stream>>>(ws1, wn1, bth1, btl1);
  k_cvt_mlp<<<64, 256, 0, stream>>>(mw0, 257, 264, w0th, w0tl);
  k_cvt_mlp<<<64, 256, 0, stream>>>(mw1, 64, 64, w1th, w1tl);
  k_cvt_x<<<(N_NODES * D / 4 + 255) / 256, 256, 0, stream>>>(x, xb, N_NODES * D / 4);

  int GB = (N_NODES + 63) / 64;     // 782
  k_agg_bf<<<(N_NODES + 7) / 8, 256, 0, stream>>>(xb, rowptr, eid16, aggn, N_NODES);
  k_sage_mfma<<<GB, 256, 0, stream>>>(x,  aggn, bth0, btl0, b0, g0, be0, rm0, rv0,
                                      h0, hb0, (unsigned short*)0, N_NODES, 0);
  k_agg_bf<<<(N_NODES + 7) / 8, 256, 0, stream>>>(hb0, rowptr, eid16, aggn, N_NODES);
  k_sage_mfma<<<GB, 256, 0, stream>>>(h0, aggn, bth1, btl1, b1, g1, be1, rm1, rv1,
                                      (float*)0, hb1h, hb1l, N_NODES, 1);

  k_mlp_mfma<<<(N_CAND + 127) / 128, 256, 0, stream>>>(hb1h, hb1l, cu, cv, cf,
      w0th, w0tl, mw0, mb0, w1th, w1tl, mb1, mw2, mb2, out, N_CAND);

  k_red1<<<256, 256, 0, stream>>>(out, bmax, bsumF, N_CAND);
  k_red2<<<1, 256, 0, stream>>>(bmax, bsumF, gred, 256);
  k_red3<<<(N_CAND + 255) / 256, 256, 0, stream>>>(out, gred, out + N_CAND, N_CAND);
}

// Round 11
// 227.621 us; speedup vs baseline: 1.0556x; 1.0114x over previous
//
#include <hip/hip_runtime.h>
#include <math.h>

#define N_NODES 50000
#define N_EDGES 800000
#define N_CAND  100000
#define D       128
#define BN_EPS  1e-5f
#define SLOPE   0.01f

// tiled-binning CSR build
#define NB2     196      // coarse buckets of 256 nodes (d >> 8), covers 50176
#define TILE    4096     // edges per k_bin block
#define NTILE   196      // 196 * 4096 = 802816 >= E
#define BCAP    4736     // per-bucket capacity: mean 4096, +10 sigma

typedef __attribute__((ext_vector_type(8))) short bf16x8;
typedef __attribute__((ext_vector_type(4))) float f32x4;

__device__ __forceinline__ float lrelu(float x){ return x >= 0.f ? x : SLOPE * x; }

__device__ __forceinline__ unsigned short f2bf_rn(float f){
  unsigned int u = __float_as_uint(f);
  unsigned int r = u + 0x7FFFu + ((u >> 16) & 1u);
  return (unsigned short)(r >> 16);
}
__device__ __forceinline__ float bf2f(unsigned short h){
  return __uint_as_float(((unsigned int)h) << 16);
}
__device__ __forceinline__ float bfu(unsigned u){ return __uint_as_float(u << 16); }        // low bf16 of word
__device__ __forceinline__ float bfh(unsigned u){ return __uint_as_float(u & 0xffff0000u); } // high bf16 of word
__device__ __forceinline__ float4 bf4f(ushort4 u){
  return make_float4(__uint_as_float((unsigned)u.x << 16),
                     __uint_as_float((unsigned)u.y << 16),
                     __uint_as_float((unsigned)u.z << 16),
                     __uint_as_float((unsigned)u.w << 16));
}

// pack 2 f32 -> 2 bf16 in one inst
__device__ __forceinline__ unsigned pk_bf16(float a, float b){
  unsigned r;
  asm("v_cvt_pk_bf16_f32 %0, %1, %2" : "=v"(r) : "v"(a), "v"(b));
  return r;
}
// split pair into hi + lo ( lo = rn(x - hi) -> self-correcting wrt cvt rounding )
__device__ __forceinline__ void split2(float a, float b, unsigned &h, unsigned &l){
  h = pk_bf16(a, b);
  float ra = a - __uint_as_float(h << 16);
  float rb = b - __uint_as_float(h & 0xffff0000u);
  l = pk_bf16(ra, rb);
}

// ---------------- CSR build: LDS-staged tiled binning ----------------
__global__ __launch_bounds__(256) void k_bin(const int* __restrict__ src, const int* __restrict__ dst,
                                             int* __restrict__ gcnt, unsigned* __restrict__ ebin, int E){
  __shared__ unsigned stage[TILE];
  __shared__ int hist[256], lscan[256], lex[256], lcur[256], gbase[256];
  __shared__ int stot;
  int t = threadIdx.x;
  int e0 = blockIdx.x * TILE;

  hist[t] = 0;
  __syncthreads();

  unsigned pk[16]; int bk[16]; bool ok[16];
  #pragma unroll
  for (int j = 0; j < 16; ++j){
    int i = e0 + j * 256 + t;
    ok[j] = (i < E);
    if (ok[j]){
      int d = dst[i];
      pk[j] = ((unsigned)d << 16) | (unsigned)src[i];
      bk[j] = d >> 8;
      atomicAdd(&hist[bk[j]], 1);
    }
  }
  __syncthreads();

  lscan[t] = hist[t];
  __syncthreads();
  for (int off = 1; off < 256; off <<= 1){
    int v = (t >= off) ? lscan[t - off] : 0;
    __syncthreads();
    lscan[t] += v;
    __syncthreads();
  }
  int ex = lscan[t] - hist[t];
  lex[t]  = ex;
  lcur[t] = ex;
  if (t < NB2) gbase[t] = hist[t] ? atomicAdd(&gcnt[t], hist[t]) : 0;
  if (t == 255) stot = lscan[255];
  __syncthreads();

  #pragma unroll
  for (int j = 0; j < 16; ++j){
    if (ok[j]){
      int p = atomicAdd(&lcur[bk[j]], 1);
      stage[p] = pk[j];
    }
  }
  __syncthreads();

  int tot = stot;
  for (int i = t; i < tot; i += 256){
    unsigned e = stage[i];
    int b = (int)(e >> 24);
    ebin[(size_t)b * BCAP + gbase[b] + (i - lex[b])] = e;
  }
}

__global__ __launch_bounds__(256) void k_bscan2(const int* __restrict__ gcnt, int* __restrict__ bbase,
                                                int* __restrict__ rowptr){
  __shared__ int sd[256];
  int t = threadIdx.x;
  int v = (t < NB2) ? gcnt[t] : 0;
  sd[t] = v; __syncthreads();
  for (int off = 1; off < 256; off <<= 1){
    int a = (t >= off) ? sd[t - off] : 0;
    __syncthreads();
    sd[t] += a; __syncthreads();
  }
  if (t < NB2) bbase[t] = sd[t] - v;
  if (t == NB2 - 1) rowptr[N_NODES] = sd[t];
}

__global__ __launch_bounds__(256) void k_bfin(const int* __restrict__ gcnt, const int* __restrict__ bbase,
                                              const unsigned* __restrict__ ebin,
                                              unsigned short* __restrict__ eid16,
                                              int* __restrict__ rowptr, int n){
  __shared__ int hist[256], lb[256], lcur[256];
  int t = threadIdx.x, b = blockIdx.x;
  int cb   = gcnt[b];
  int base = bbase[b];
  const unsigned* eb = &ebin[(size_t)b * BCAP];
  hist[t] = 0;
  __syncthreads();
  for (int idx = t; idx < cb; idx += 256) atomicAdd(&hist[(eb[idx] >> 16) & 255], 1);
  __syncthreads();
  lb[t] = hist[t];
  __syncthreads();
  for (int off = 1; off < 256; off <<= 1){
    int v = (t >= off) ? lb[t - off] : 0;
    __syncthreads();
    lb[t] += v; __syncthreads();
  }
  int ex = lb[t] - hist[t];
  lcur[t] = ex;
  int node = (b << 8) + t;
  if (node < n) rowptr[node] = base + ex;
  __syncthreads();
  for (int idx = t; idx < cb; idx += 256){
    unsigned e = eb[idx];
    int p = atomicAdd(&lcur[(e >> 16) & 255], 1);
    eid16[base + p] = (unsigned short)(e & 0xffffu);
  }
}

// ---------------- weight transpose + bf16 hi/lo split (SAGE) ----------------
__global__ __launch_bounds__(256) void k_cvt_w(const float* __restrict__ ws, const float* __restrict__ wn,
                                               unsigned short* __restrict__ bth, unsigned short* __restrict__ btl){
  int col = blockIdx.x;       // 0..127
  int k   = threadIdx.x;      // 0..255
  float v = (k < 128) ? ws[k * D + col] : wn[(k - 128) * D + col];
  unsigned short hi = f2bf_rn(v);
  unsigned short lo = f2bf_rn(v - bf2f(hi));
  bth[col * 256 + k] = hi;
  btl[col * 256 + k] = lo;
}

// ---------------- MLP W1 transpose + split: w[64 x 64] -> T_h/T_l [64][64] ----------------
__global__ __launch_bounds__(256) void k_cvt_mlp(const float* __restrict__ w, int K, int Kpad,
                                                 unsigned short* __restrict__ th, unsigned short* __restrict__ tl){
  int col = blockIdx.x;       // 0..63
  for (int k = threadIdx.x; k < Kpad; k += 256){
    float v = (k < K) ? w[k * 64 + col] : 0.f;
    unsigned short hi = f2bf_rn(v);
    th[col * Kpad + k] = hi;
    tl[col * Kpad + k] = f2bf_rn(v - bf2f(hi));
  }
}

// ---------------- W0cat = [W0u | W0v] transpose + split: -> [128 cols][128 k] ----------------
__global__ __launch_bounds__(128) void k_cvt_w0cat(const float* __restrict__ mw0,
                                                   unsigned short* __restrict__ ch, unsigned short* __restrict__ cl_){
  int col = blockIdx.x;       // 0..127  (0:63 -> W0u cols, 64:127 -> W0v cols)
  int k   = threadIdx.x;      // 0..127
  float v = (col < 64) ? mw0[k * 64 + col] : mw0[(128 + k) * 64 + (col - 64)];
  unsigned short hi = f2bf_rn(v);
  ch [col * 128 + k] = hi;
  cl_[col * 128 + k] = f2bf_rn(v - bf2f(hi));
}

// ---------------- x -> bf16 plane ----------------
__global__ __launch_bounds__(256) void k_cvt_x(const float* __restrict__ X, unsigned short* __restrict__ XB, int nel4){
  int i = blockIdx.x * 256 + threadIdx.x;
  if (i < nel4){
    float4 v = *reinterpret_cast<const float4*>(&X[(size_t)i * 4]);
    ushort4 u;
    u.x = f2bf_rn(v.x); u.y = f2bf_rn(v.y); u.z = f2bf_rn(v.z); u.w = f2bf_rn(v.w);
    *reinterpret_cast<ushort4*>(&XB[(size_t)i * 4]) = u;
  }
}

// ---------------- mean aggregation: bf16 gather, fp32 accumulate ----------------
__global__ __launch_bounds__(256) void k_agg_bf(const unsigned short* __restrict__ XB,
                                                const int* __restrict__ rowptr, const unsigned short* __restrict__ eid,
                                                float* __restrict__ AG, int n){
  int g = blockIdx.x * 8 + (threadIdx.x >> 5);   // node
  int l = threadIdx.x & 31;                      // 4-bf16 chunk
  if (g >= n) return;
  int e0 = rowptr[g], e1 = rowptr[g + 1];
  float4 a0 = make_float4(0.f,0.f,0.f,0.f);
  float4 a1 = make_float4(0.f,0.f,0.f,0.f);
  float4 a2 = make_float4(0.f,0.f,0.f,0.f);
  float4 a3 = make_float4(0.f,0.f,0.f,0.f);
  int e = e0;
  for (; e + 4 <= e1; e += 4){
    int s0 = eid[e], s1 = eid[e + 1], s2 = eid[e + 2], s3 = eid[e + 3];
    ushort4 u0 = *reinterpret_cast<const ushort4*>(&XB[(size_t)s0 * D + l * 4]);
    ushort4 u1 = *reinterpret_cast<const ushort4*>(&XB[(size_t)s1 * D + l * 4]);
    ushort4 u2 = *reinterpret_cast<const ushort4*>(&XB[(size_t)s2 * D + l * 4]);
    ushort4 u3 = *reinterpret_cast<const ushort4*>(&XB[(size_t)s3 * D + l * 4]);
    float4 f0 = bf4f(u0), f1 = bf4f(u1), f2 = bf4f(u2), f3 = bf4f(u3);
    a0.x += f0.x; a0.y += f0.y; a0.z += f0.z; a0.w += f0.w;
    a1.x += f1.x; a1.y += f1.y; a1.z += f1.z; a1.w += f1.w;
    a2.x += f2.x; a2.y += f2.y; a2.z += f2.z; a2.w += f2.w;
    a3.x += f3.x; a3.y += f3.y; a3.z += f3.z; a3.w += f3.w;
  }
  for (; e < e1; ++e){
    int s0 = eid[e];
    ushort4 u0 = *reinterpret_cast<const ushort4*>(&XB[(size_t)s0 * D + l * 4]);
    float4 f0 = bf4f(u0);
    a0.x += f0.x; a0.y += f0.y; a0.z += f0.z; a0.w += f0.w;
  }
  float sc = 1.f / fmaxf((float)(e1 - e0), 1.f);
  float4 o;
  o.x = (a0.x + a1.x + a2.x + a3.x) * sc;
  o.y = (a0.y + a1.y + a2.y + a3.y) * sc;
  o.z = (a0.z + a1.z + a2.z + a3.z) * sc;
  o.w = (a0.w + a1.w + a2.w + a3.w) * sc;
  *reinterpret_cast<float4*>(&AG[(size_t)g * D + l * 4]) = o;
}

// ---------------- SAGE layer via split-bf16 MFMA ----------------
__global__ __launch_bounds__(256) void k_sage_mfma(const float* __restrict__ XS, const float* __restrict__ AG,
    const unsigned short* __restrict__ BTH, const unsigned short* __restrict__ BTL,
    const float* __restrict__ Bb, const float* __restrict__ GM, const float* __restrict__ BT,
    const float* __restrict__ RM, const float* __restrict__ RV,
    float* __restrict__ H, unsigned short* __restrict__ HBH, unsigned short* __restrict__ HBL,
    int n, int donan)
{
  __shared__ unsigned short Ah[64 * 40];
  __shared__ unsigned short Al[64 * 40];
  __shared__ unsigned short Bh[128 * 40];
  __shared__ unsigned short Bl[128 * 40];

  int t  = threadIdx.x;
  int l  = t & 63;
  int wv = t >> 6;
  int lm = l & 15;
  int lk = l >> 4;
  int node0 = blockIdx.x * 64;

  f32x4 acc[8];
  #pragma unroll
  for (int f = 0; f < 8; ++f) acc[f] = (f32x4){0.f, 0.f, 0.f, 0.f};

  for (int step = 0; step < 8; ++step){
    int k0 = step * 32;
    const float* srcA = (step < 4) ? XS : AG;
    int koff = (step < 4) ? k0 : (k0 - 128);

    __syncthreads();
    #pragma unroll
    for (int i = 0; i < 2; ++i){
      int c   = t + i * 256;
      int row = c >> 3, c4 = c & 7;
      int node = min(node0 + row, n - 1);
      float4 v = *reinterpret_cast<const float4*>(&srcA[(size_t)node * D + koff + c4 * 4]);
      const float* vp = (const float*)&v;
      unsigned short hh[4], ll[4];
      #pragma unroll
      for (int j = 0; j < 4; ++j){
        unsigned short hi = f2bf_rn(vp[j]);
        hh[j] = hi;
        ll[j] = f2bf_rn(vp[j] - bf2f(hi));
      }
      uint2 wh, wl;
      wh.x = (unsigned)hh[0] | ((unsigned)hh[1] << 16);
      wh.y = (unsigned)hh[2] | ((unsigned)hh[3] << 16);
      wl.x = (unsigned)ll[0] | ((unsigned)ll[1] << 16);
      wl.y = (unsigned)ll[2] | ((unsigned)ll[3] << 16);
      *reinterpret_cast<uint2*>(&Ah[row * 40 + c4 * 4]) = wh;
      *reinterpret_cast<uint2*>(&Al[row * 40 + c4 * 4]) = wl;
    }
    #pragma unroll
    for (int i = 0; i < 2; ++i){
      int c   = t + i * 256;
      int col = c >> 2, q = c & 3;
      *reinterpret_cast<uint4*>(&Bh[col * 40 + q * 8]) =
          *reinterpret_cast<const uint4*>(&BTH[col * 256 + k0 + q * 8]);
      *reinterpret_cast<uint4*>(&Bl[col * 40 + q * 8]) =
          *reinterpret_cast<const uint4*>(&BTL[col * 256 + k0 + q * 8]);
    }
    __syncthreads();

    bf16x8 afh = *reinterpret_cast<const bf16x8*>(&Ah[(wv * 16 + lm) * 40 + lk * 8]);
    bf16x8 afl = *reinterpret_cast<const bf16x8*>(&Al[(wv * 16 + lm) * 40 + lk * 8]);
    #pragma unroll
    for (int f = 0; f < 8; ++f){
      bf16x8 bfh = *reinterpret_cast<const bf16x8*>(&Bh[(f * 16 + lm) * 40 + lk * 8]);
      bf16x8 bfl = *reinterpret_cast<const bf16x8*>(&Bl[(f * 16 + lm) * 40 + lk * 8]);
      acc[f] = __builtin_amdgcn_mfma_f32_16x16x32_bf16(afh, bfh, acc[f], 0, 0, 0);
      acc[f] = __builtin_amdgcn_mfma_f32_16x16x32_bf16(afl, bfh, acc[f], 0, 0, 0);
      acc[f] = __builtin_amdgcn_mfma_f32_16x16x32_bf16(afh, bfl, acc[f], 0, 0, 0);
    }
  }

  #pragma unroll
  for (int f = 0; f < 8; ++f){
    int col = f * 16 + lm;
    float s  = GM[col] * rsqrtf(RV[col] + BN_EPS);
    float cj = (Bb[col] - RM[col]) * s + BT[col];
    #pragma unroll
    for (int r = 0; r < 4; ++r){
      int node = node0 + wv * 16 + lk * 4 + r;
      if (node < n){
        float v = lrelu(acc[f][r] * s + cj);
        if (donan && (v != v)) v = 1e-14f;
        if (H)  H[(size_t)node * D + col] = v;
        unsigned short h16 = f2bf_rn(v);
        if (HBH) HBH[(size_t)node * D + col] = h16;
        if (HBL) HBL[(size_t)node * D + col] = f2bf_rn(v - bf2f(h16));
      }
    }
  }
}

// ---------------- P = h1 @ [W0u | W0v]  (50k x 128, dense GEMM) ----------------
// A direct from pre-split hb1 planes (no split needed), B from pre-split
// W0cat. 4 k-steps, 96 MFMAs/wave. Output pre-split P planes (no bias/act —
// added per-candidate in k_mlp2). This factors the MLP L1 through the 50k
// nodes instead of 100k x 2 candidate rows: 4x fewer FLOPs, and k_mlp2's
// gather shrinks to the 256B half-row of P each side actually needs.
__global__ __launch_bounds__(256) void k_pgemm(
    const unsigned short* __restrict__ HH, const unsigned short* __restrict__ HL,
    const unsigned short* __restrict__ WCH, const unsigned short* __restrict__ WCL,
    unsigned short* __restrict__ PH, unsigned short* __restrict__ PL, int n)
{
  __shared__ unsigned short Ah[64 * 40];
  __shared__ unsigned short Al[64 * 40];
  __shared__ unsigned short Bh[128 * 40];
  __shared__ unsigned short Bl[128 * 40];

  int t  = threadIdx.x;
  int l  = t & 63;
  int wv = t >> 6;
  int lm = l & 15;
  int lk = l >> 4;
  int node0 = blockIdx.x * 64;

  f32x4 acc[8];
  #pragma unroll
  for (int f = 0; f < 8; ++f) acc[f] = (f32x4){0.f, 0.f, 0.f, 0.f};

  for (int step = 0; step < 4; ++step){
    int k0 = step * 32;
    __syncthreads();
    {  // stage A: 64 rows x 32 k (256 x 16B chunks, one per thread)
      int row = t >> 2, q = t & 3;
      int node = min(node0 + row, n - 1);
      *reinterpret_cast<uint4*>(&Ah[row * 40 + q * 8]) =
          *reinterpret_cast<const uint4*>(&HH[(size_t)node * D + k0 + q * 8]);
      *reinterpret_cast<uint4*>(&Al[row * 40 + q * 8]) =
          *reinterpret_cast<const uint4*>(&HL[(size_t)node * D + k0 + q * 8]);
    }
    #pragma unroll
    for (int i = 0; i < 2; ++i){  // stage B: 128 cols x 32 k
      int c = t + i * 256;
      int col = c >> 2, q = c & 3;
      *reinterpret_cast<uint4*>(&Bh[col * 40 + q * 8]) =
          *reinterpret_cast<const uint4*>(&WCH[col * 128 + k0 + q * 8]);
      *reinterpret_cast<uint4*>(&Bl[col * 40 + q * 8]) =
          *reinterpret_cast<const uint4*>(&WCL[col * 128 + k0 + q * 8]);
    }
    __syncthreads();

    bf16x8 afh = *reinterpret_cast<const bf16x8*>(&Ah[(wv * 16 + lm) * 40 + lk * 8]);
    bf16x8 afl = *reinterpret_cast<const bf16x8*>(&Al[(wv * 16 + lm) * 40 + lk * 8]);
    #pragma unroll
    for (int f = 0; f < 8; ++f){
      bf16x8 bfh = *reinterpret_cast<const bf16x8*>(&Bh[(f * 16 + lm) * 40 + lk * 8]);
      bf16x8 bfl = *reinterpret_cast<const bf16x8*>(&Bl[(f * 16 + lm) * 40 + lk * 8]);
      acc[f] = __builtin_amdgcn_mfma_f32_16x16x32_bf16(afh, bfh, acc[f], 0, 0, 0);
      acc[f] = __builtin_amdgcn_mfma_f32_16x16x32_bf16(afl, bfh, acc[f], 0, 0, 0);
      acc[f] = __builtin_amdgcn_mfma_f32_16x16x32_bf16(afh, bfl, acc[f], 0, 0, 0);
    }
  }

  #pragma unroll
  for (int f = 0; f < 8; ++f){
    int col = f * 16 + lm;
    #pragma unroll
    for (int r = 0; r < 4; ++r){
      int node = node0 + wv * 16 + lk * 4 + r;
      if (node < n){
        float v = acc[f][r];
        unsigned short h16 = f2bf_rn(v);
        PH[(size_t)node * D + col] = h16;
        PL[(size_t)node * D + col] = f2bf_rn(v - bf2f(h16));
      }
    }
  }
}

// process one u32 word (2 cols) of each P stream -> split-bf16 z pair
__device__ __forceinline__ void proc2(unsigned uh, unsigned ul, unsigned vh, unsigned vl,
                                      float wfa, float wfb, float b0a, float b0b, float cfv,
                                      unsigned &ho, unsigned &lo_){
  float z0 = lrelu(bfu(uh) + bfu(ul) + bfu(vh) + bfu(vl) + cfv * wfa + b0a);
  float z1 = lrelu(bfh(uh) + bfh(ul) + bfh(vh) + bfh(vl) + cfv * wfb + b0b);
  split2(z0, z1, ho, lo_);
}

// ---------------- candidate MLP tail: gather P + L2 + L3 ----------------
// 128 cands/block, 4 waves x 32 cands. Lane l: cand cl=l&31, half hsel=l>>5
// (cols hsel*32..+32). 16 INDEPENDENT 16B gathers per lane (u/v x hi/lo),
// no MFMA on the gather path. a1 = Pu[cu][col] + Pv[cv][64+col] + cf*wf + b0
// -> lrelu -> split-bf16 z in LDS -> L2 (K=64 MFMA) -> L3 (dot + reduce).
__global__ __launch_bounds__(256) void k_mlp2(
    const unsigned short* __restrict__ PH, const unsigned short* __restrict__ PL,
    const int* __restrict__ cu, const int* __restrict__ cv, const float* __restrict__ cf,
    const float* __restrict__ mw0, const float* __restrict__ mb0,
    const unsigned short* __restrict__ W1H, const unsigned short* __restrict__ W1L,
    const float* __restrict__ mb1, const float* __restrict__ mw2, const float* __restrict__ mb2,
    float* __restrict__ y, int C)
{
  __shared__ unsigned short zh[4][32 * 72];
  __shared__ unsigned short zl[4][32 * 72];
  __shared__ float bw[64], ww[64];

  int t = threadIdx.x;
  int wv = t >> 6, l = t & 63, lm = l & 15, lk = l >> 4;
  int cl = l & 31, hsel = l >> 5;
  int candbase = blockIdx.x * 128 + wv * 32;

  if (t < 64){ bw[t] = mb0[t]; ww[t] = mw0[256 * 64 + t]; }
  __syncthreads();

  int cc = min(candbase + cl, C - 1);
  int nu = cu[cc], nv = cv[cc];
  float cfv = cf[cc];

  // ---- gather: 16 independent 16B loads ----
  const uint4* puh = reinterpret_cast<const uint4*>(&PH[(size_t)nu * D + hsel * 32]);
  const uint4* pul = reinterpret_cast<const uint4*>(&PL[(size_t)nu * D + hsel * 32]);
  const uint4* pvh = reinterpret_cast<const uint4*>(&PH[(size_t)nv * D + 64 + hsel * 32]);
  const uint4* pvl = reinterpret_cast<const uint4*>(&PL[(size_t)nv * D + 64 + hsel * 32]);
  uint4 uh0 = puh[0], uh1 = puh[1], uh2 = puh[2], uh3 = puh[3];
  uint4 ul0 = pul[0], ul1 = pul[1], ul2 = pul[2], ul3 = pul[3];
  uint4 vh0 = pvh[0], vh1 = pvh[1], vh2 = pvh[2], vh3 = pvh[3];
  uint4 vl0 = pvl[0], vl1 = pvl[1], vl2 = pvl[2], vl3 = pvl[3];

  int colb = hsel * 32;
  unsigned short* zhr = &zh[wv][cl * 72];
  unsigned short* zlr = &zl[wv][cl * 72];
  #define PROC_W(UH, UL, VH, VL, CO) { \
    unsigned ho, lo_; \
    proc2(UH, UL, VH, VL, ww[colb + (CO)], ww[colb + (CO) + 1], bw[colb + (CO)], bw[colb + (CO) + 1], cfv, ho, lo_); \
    *reinterpret_cast<unsigned*>(&zhr[colb + (CO)]) = ho; \
    *reinterpret_cast<unsigned*>(&zlr[colb + (CO)]) = lo_; }
  PROC_W(uh0.x, ul0.x, vh0.x, vl0.x, 0)  PROC_W(uh0.y, ul0.y, vh0.y, vl0.y, 2)
  PROC_W(uh0.z, ul0.z, vh0.z, vl0.z, 4)  PROC_W(uh0.w, ul0.w, vh0.w, vl0.w, 6)
  PROC_W(uh1.x, ul1.x, vh1.x, vl1.x, 8)  PROC_W(uh1.y, ul1.y, vh1.y, vl1.y, 10)
  PROC_W(uh1.z, ul1.z, vh1.z, vl1.z, 12) PROC_W(uh1.w, ul1.w, vh1.w, vl1.w, 14)
  PROC_W(uh2.x, ul2.x, vh2.x, vl2.x, 16) PROC_W(uh2.y, ul2.y, vh2.y, vl2.y, 18)
  PROC_W(uh2.z, ul2.z, vh2.z, vl2.z, 20) PROC_W(uh2.w, ul2.w, vh2.w, vl2.w, 22)
  PROC_W(uh3.x, ul3.x, vh3.x, vl3.x, 24) PROC_W(uh3.y, ul3.y, vh3.y, vl3.y, 26)
  PROC_W(uh3.z, ul3.z, vh3.z, vl3.z, 28) PROC_W(uh3.w, ul3.w, vh3.w, vl3.w, 30)
  #undef PROC_W
  // wave-local LDS: hardware lgkmcnt ordering covers write->read, no barrier

  // ---- layer 2: K = 64 via MFMA (2 M-frags: rows lm, lm+16) ----
  int kbase = lk * 8;
  f32x4 a2[2][4];
  #pragma unroll
  for (int m = 0; m < 2; ++m)
    #pragma unroll
    for (int f = 0; f < 4; ++f) a2[m][f] = (f32x4){0.f, 0.f, 0.f, 0.f};

  #pragma unroll
  for (int s2 = 0; s2 < 2; ++s2){
    int kk = s2 * 32 + kbase;
    bf16x8 azh0 = *reinterpret_cast<const bf16x8*>(&zh[wv][(0 * 16 + lm) * 72 + kk]);
    bf16x8 azl0 = *reinterpret_cast<const bf16x8*>(&zl[wv][(0 * 16 + lm) * 72 + kk]);
    bf16x8 azh1 = *reinterpret_cast<const bf16x8*>(&zh[wv][(1 * 16 + lm) * 72 + kk]);
    bf16x8 azl1 = *reinterpret_cast<const bf16x8*>(&zl[wv][(1 * 16 + lm) * 72 + kk]);
    #pragma unroll
    for (int f = 0; f < 4; ++f){
      int col = f * 16 + lm;
      bf16x8 bh = *reinterpret_cast<const bf16x8*>(&W1H[(size_t)col * 64 + kk]);
      bf16x8 bl = *reinterpret_cast<const bf16x8*>(&W1L[(size_t)col * 64 + kk]);
      a2[0][f] = __builtin_amdgcn_mfma_f32_16x16x32_bf16(azh0, bh, a2[0][f], 0, 0, 0);
      a2[0][f] = __builtin_amdgcn_mfma_f32_16x16x32_bf16(azl0, bh, a2[0][f], 0, 0, 0);
      a2[0][f] = __builtin_amdgcn_mfma_f32_16x16x32_bf16(azh0, bl, a2[0][f], 0, 0, 0);
      a2[1][f] = __builtin_amdgcn_mfma_f32_16x16x32_bf16(azh1, bh, a2[1][f], 0, 0, 0);
      a2[1][f] = __builtin_amdgcn_mfma_f32_16x16x32_bf16(azl1, bh, a2[1][f], 0, 0, 0);
      a2[1][f] = __builtin_amdgcn_mfma_f32_16x16x32_bf16(azh1, bl, a2[1][f], 0, 0, 0);
    }
  }

  // ---- layer 3: 64 -> 1 ----
  float p00 = 0.f, p01 = 0.f, p02 = 0.f, p03 = 0.f;
  float p10 = 0.f, p11 = 0.f, p12 = 0.f, p13 = 0.f;
  #pragma unroll
  for (int f = 0; f < 4; ++f){
    int col = f * 16 + lm;
    float b1v = mb1[col];
    float w2v = mw2[col];
    p00 = fmaf(lrelu(a2[0][f][0] + b1v), w2v, p00);
    p01 = fmaf(lrelu(a2[0][f][1] + b1v), w2v, p01);
    p02 = fmaf(lrelu(a2[0][f][2] + b1v), w2v, p02);
    p03 = fmaf(lrelu(a2[0][f][3] + b1v), w2v, p03);
    p10 = fmaf(lrelu(a2[1][f][0] + b1v), w2v, p10);
    p11 = fmaf(lrelu(a2[1][f][1] + b1v), w2v, p11);
    p12 = fmaf(lrelu(a2[1][f][2] + b1v), w2v, p12);
    p13 = fmaf(lrelu(a2[1][f][3] + b1v), w2v, p13);
  }
  #pragma unroll
  for (int off = 1; off < 16; off <<= 1){
    p00 += __shfl_xor(p00, off); p01 += __shfl_xor(p01, off);
    p02 += __shfl_xor(p02, off); p03 += __shfl_xor(p03, off);
    p10 += __shfl_xor(p10, off); p11 += __shfl_xor(p11, off);
    p12 += __shfl_xor(p12, off); p13 += __shfl_xor(p13, off);
  }
  if (lm == 0){
    float b2 = mb2[0];
    int base0 = candbase + lk * 4;
    int base1 = candbase + 16 + lk * 4;
    if (base0 + 0 < C) y[base0 + 0] = p00 + b2;
    if (base0 + 1 < C) y[base0 + 1] = p01 + b2;
    if (base0 + 2 < C) y[base0 + 2] = p02 + b2;
    if (base0 + 3 < C) y[base0 + 3] = p03 + b2;
    if (base1 + 0 < C) y[base1 + 0] = p10 + b2;
    if (base1 + 1 < C) y[base1 + 1] = p11 + b2;
    if (base1 + 2 < C) y[base1 + 2] = p12 + b2;
    if (base1 + 3 < C) y[base1 + 3] = p13 + b2;
  }
}

// ---------------- softmax over C logits ----------------
__global__ __launch_bounds__(256) void k_red1(const float* __restrict__ y,
                                              float* __restrict__ bmax, float* __restrict__ bsum, int C){
  __shared__ float sm[4];
  __shared__ float ss[4];
  int t = threadIdx.x;
  float m = -3.4e38f;
  for (int i = blockIdx.x * 256 + t; i < C; i += gridDim.x * 256) m = fmaxf(m, y[i]);
  for (int o = 32; o; o >>= 1) m = fmaxf(m, __shfl_xor(m, o));
  if ((t & 63) == 0) sm[t >> 6] = m;
  __syncthreads();
  float bm = fmaxf(fmaxf(sm[0], sm[1]), fmaxf(sm[2], sm[3]));
  float s = 0.f;
  for (int i = blockIdx.x * 256 + t; i < C; i += gridDim.x * 256) s += expf(y[i] - bm);
  for (int o = 32; o; o >>= 1) s += __shfl_xor(s, o);
  if ((t & 63) == 0) ss[t >> 6] = s;
  __syncthreads();
  if (t == 0){ bmax[blockIdx.x] = bm; bsum[blockIdx.x] = ss[0] + ss[1] + ss[2] + ss[3]; }
}

__global__ __launch_bounds__(256) void k_red2(const float* __restrict__ bmax, const float* __restrict__ bsum,
                                              float* __restrict__ g, int nb){
  __shared__ float sm[4];
  __shared__ float ss[4];
  int t = threadIdx.x;
  float m0 = (t < nb) ? bmax[t] : -3.4e38f;
  float m = m0;
  for (int o = 32; o; o >>= 1) m = fmaxf(m, __shfl_xor(m, o));
  if ((t & 63) == 0) sm[t >> 6] = m;
  __syncthreads();
  float gm = fmaxf(fmaxf(sm[0], sm[1]), fmaxf(sm[2], sm[3]));
  float s = (t < nb) ? bsum[t] * expf(m0 - gm) : 0.f;
  for (int o = 32; o; o >>= 1) s += __shfl_xor(s, o);
  if ((t & 63) == 0) ss[t >> 6] = s;
  __syncthreads();
  if (t == 0){ g[0] = gm; g[1] = 1.f / (ss[0] + ss[1] + ss[2] + ss[3]); }
}

__global__ __launch_bounds__(256) void k_red3(const float* __restrict__ y, const float* __restrict__ g,
                                              float* __restrict__ out, int C){
  int i = blockIdx.x * 256 + threadIdx.x;
  if (i < C) out[i] = expf(y[i] - g[0]) * g[1];
}

extern "C" void kernel_launch(void* const* d_in, const int* in_sizes, int n_in,
                              void* d_out, int out_size, void* d_ws, size_t ws_size,
                              hipStream_t stream)
{
  const float* x   = (const float*)d_in[0];
  const int*   src = (const int*)  d_in[1];
  const int*   dst = (const int*)  d_in[2];
  const int*   cu  = (const int*)  d_in[3];
  const int*   cv  = (const int*)  d_in[4];
  const float* cf  = (const float*)d_in[5];
  const float* ws0 = (const float*)d_in[6];
  const float* wn0 = (const float*)d_in[7];
  const float* b0  = (const float*)d_in[8];
  const float* g0  = (const float*)d_in[9];
  const float* be0 = (const float*)d_in[10];
  const float* rm0 = (const float*)d_in[11];
  const float* rv0 = (const float*)d_in[12];
  const float* ws1 = (const float*)d_in[13];
  const float* wn1 = (const float*)d_in[14];
  const float* b1  = (const float*)d_in[15];
  const float* g1  = (const float*)d_in[16];
  const float* be1 = (const float*)d_in[17];
  const float* rm1 = (const float*)d_in[18];
  const float* rv1 = (const float*)d_in[19];
  const float* mw0 = (const float*)d_in[20];
  const float* mb0 = (const float*)d_in[21];
  const float* mw1 = (const float*)d_in[22];
  const float* mb1 = (const float*)d_in[23];
  const float* mw2 = (const float*)d_in[24];
  const float* mb2 = (const float*)d_in[25];

  float* out = (float*)d_out;   // [C] y then [C] softmax

  char* w = (char*)d_ws;
  float* aggn  = (float*)w; w += (size_t)N_NODES * D * 4;      // -> P planes after sage1
  float* h0    = (float*)w; w += (size_t)N_NODES * D * 4;
  float* h1    = (float*)w; w += (size_t)N_NODES * D * 4;
  int* cnt     = (int*)w;   w += (size_t)N_NODES * 4;          // -> SAGE weights L0
  int* rowptr  = (int*)w;   w += (size_t)(N_NODES + 1) * 4;
  int* cur     = (int*)w;   w += (size_t)N_NODES * 4;          // -> SAGE weights L1
  int* eid     = (int*)w;   w += (size_t)N_EDGES * 4;          // holds eid16 (ushort)
  int* gcnt    = (int*)w;   w += (size_t)(NB2 + 8) * 4;
  int* bbase   = (int*)w;   w += (size_t)(NB2 + 1) * 4;
  float* bmax  = (float*)w; w += 256 * 4;
  float* bsumF = (float*)w; w += 256 * 4;
  float* gred  = (float*)w; w += 2 * 4;
  // split W1 (transposed [64][64]) and W0cat ([128][128])
  unsigned short* w1th  = (unsigned short*)w; w += (size_t)64 * 64 * 2;
  unsigned short* w1tl  = (unsigned short*)w; w += (size_t)64 * 64 * 2;
  unsigned short* w0cth = (unsigned short*)w; w += (size_t)128 * 128 * 2;
  unsigned short* w0ctl = (unsigned short*)w; w += (size_t)128 * 128 * 2;

  unsigned short* eid16 = (unsigned short*)eid;

  // edge bins OVERLAY h0 (h0 only live sage0 -> sage1, after CSR build):
  unsigned* ebin = (unsigned*)h0;      // NB2*BCAP*4 = 3.7 MB << 25.6 MB

  // h1 region timeline:
  //   [cvt_x .. agg0] : xb ; [sage0 .. agg1] : hb0 ; [sage1 .. pgemm] : hb1h/hb1l
  unsigned short* xb   = (unsigned short*)h1;
  unsigned short* hb0  = xb + (size_t)N_NODES * D;
  unsigned short* hb1h = (unsigned short*)h1;
  unsigned short* hb1l = hb1h + (size_t)N_NODES * D;

  // P planes OVERLAY aggn (dead after sage1 reads it):
  unsigned short* pbh = (unsigned short*)aggn;
  unsigned short* pbl = pbh + (size_t)N_NODES * D;

  // split-bf16 SAGE weight buffers alias the cnt/cur scratch:
  unsigned short* bth0 = (unsigned short*)cnt;
  unsigned short* btl0 = bth0 + 128 * 256;
  unsigned short* bth1 = (unsigned short*)cur;
  unsigned short* btl1 = bth1 + 128 * 256;

  // ---- CSR build (tiled LDS binning) ----
  hipMemsetAsync(gcnt, 0, (size_t)NB2 * 4, stream);
  k_bin   <<<NTILE, 256, 0, stream>>>(src, dst, gcnt, ebin, N_EDGES);
  k_bscan2<<<1, 256, 0, stream>>>(gcnt, bbase, rowptr);
  k_bfin  <<<NB2, 256, 0, stream>>>(gcnt, bbase, ebin, eid16, rowptr, N_NODES);

  // ---- weight conversions (independent) ----
  k_cvt_w<<<128, 256, 0, stream>>>(ws0, wn0, bth0, btl0);
  k_cvt_w<<<128, 256, 0, stream>>>(ws1, wn1, bth1, btl1);
  k_cvt_mlp<<<64, 256, 0, stream>>>(mw1, 64, 64, w1th, w1tl);
  k_cvt_w0cat<<<128, 128, 0, stream>>>(mw0, w0cth, w0ctl);
  k_cvt_x<<<(N_NODES * D / 4 + 255) / 256, 256, 0, stream>>>(x, xb, N_NODES * D / 4);

  int GB = (N_NODES + 63) / 64;     // 782
  k_agg_bf<<<(N_NODES + 7) / 8, 256, 0, stream>>>(xb, rowptr, eid16, aggn, N_NODES);
  k_sage_mfma<<<GB, 256, 0, stream>>>(x,  aggn, bth0, btl0, b0, g0, be0, rm0, rv0,
                                      h0, hb0, (unsigned short*)0, N_NODES, 0);
  k_agg_bf<<<(N_NODES + 7) / 8, 256, 0, stream>>>(hb0, rowptr, eid16, aggn, N_NODES);
  k_sage_mfma<<<GB, 256, 0, stream>>>(h0, aggn, bth1, btl1, b1, g1, be1, rm1, rv1,
                                      (float*)0, hb1h, hb1l, N_NODES, 1);

  k_pgemm<<<GB, 256, 0, stream>>>(hb1h, hb1l, w0cth, w0ctl, pbh, pbl, N_NODES);

  k_mlp2<<<(N_CAND + 127) / 128, 256, 0, stream>>>(pbh, pbl, cu, cv, cf,
      mw0, mb0, w1th, w1tl, mb1, mw2, mb2, out, N_CAND);

  k_red1<<<256, 256, 0, stream>>>(out, bmax, bsumF, N_CAND);
  k_red2<<<1, 256, 0, stream>>>(bmax, bsumF, gred, 256);
  k_red3<<<(N_CAND + 255) / 256, 256, 0, stream>>>(out, gred, out + N_CAND, N_CAND);
}

// Round 12
// 210.016 us; speedup vs baseline: 1.1441x; 1.0838x over previous
//
#include <hip/hip_runtime.h>
#include <math.h>

#define N_NODES 50000
#define N_EDGES 800000
#define N_CAND  100000
#define D       128
#define BN_EPS  1e-5f
#define SLOPE   0.01f

// tiled-binning CSR build
#define NB2     196
#define TILE    4096
#define NTILE   196
#define BCAP    4736

typedef __attribute__((ext_vector_type(8))) short bf16x8;
typedef __attribute__((ext_vector_type(4))) float f32x4;

__device__ __forceinline__ float lrelu(float x){ return x >= 0.f ? x : SLOPE * x; }

__device__ __forceinline__ unsigned short f2bf_rn(float f){
  unsigned int u = __float_as_uint(f);
  unsigned int r = u + 0x7FFFu + ((u >> 16) & 1u);
  return (unsigned short)(r >> 16);
}
__device__ __forceinline__ float bf2f(unsigned short h){
  return __uint_as_float(((unsigned int)h) << 16);
}
__device__ __forceinline__ float bfu(unsigned u){ return __uint_as_float(u << 16); }
__device__ __forceinline__ float bfh(unsigned u){ return __uint_as_float(u & 0xffff0000u); }
__device__ __forceinline__ float4 bf4f(ushort4 u){
  return make_float4(__uint_as_float((unsigned)u.x << 16),
                     __uint_as_float((unsigned)u.y << 16),
                     __uint_as_float((unsigned)u.z << 16),
                     __uint_as_float((unsigned)u.w << 16));
}

__device__ __forceinline__ unsigned pk_bf16(float a, float b){
  unsigned r;
  asm("v_cvt_pk_bf16_f32 %0, %1, %2" : "=v"(r) : "v"(a), "v"(b));
  return r;
}
__device__ __forceinline__ void split2(float a, float b, unsigned &h, unsigned &l){
  h = pk_bf16(a, b);
  float ra = a - __uint_as_float(h << 16);
  float rb = b - __uint_as_float(h & 0xffff0000u);
  l = pk_bf16(ra, rb);
}

// ---------------- CSR build: LDS-staged tiled binning ----------------
__global__ __launch_bounds__(256) void k_bin(const int* __restrict__ src, const int* __restrict__ dst,
                                             int* __restrict__ gcnt, unsigned* __restrict__ ebin, int E){
  __shared__ unsigned stage[TILE];
  __shared__ int hist[256], lscan[256], lex[256], lcur[256], gbase[256];
  __shared__ int stot;
  int t = threadIdx.x;
  int e0 = blockIdx.x * TILE;

  hist[t] = 0;
  __syncthreads();

  unsigned pk[16]; int bk[16]; bool ok[16];
  #pragma unroll
  for (int j = 0; j < 16; ++j){
    int i = e0 + j * 256 + t;
    ok[j] = (i < E);
    if (ok[j]){
      int d = dst[i];
      pk[j] = ((unsigned)d << 16) | (unsigned)src[i];
      bk[j] = d >> 8;
      atomicAdd(&hist[bk[j]], 1);
    }
  }
  __syncthreads();

  lscan[t] = hist[t];
  __syncthreads();
  for (int off = 1; off < 256; off <<= 1){
    int v = (t >= off) ? lscan[t - off] : 0;
    __syncthreads();
    lscan[t] += v;
    __syncthreads();
  }
  int ex = lscan[t] - hist[t];
  lex[t]  = ex;
  lcur[t] = ex;
  if (t < NB2) gbase[t] = hist[t] ? atomicAdd(&gcnt[t], hist[t]) : 0;
  if (t == 255) stot = lscan[255];
  __syncthreads();

  #pragma unroll
  for (int j = 0; j < 16; ++j){
    if (ok[j]){
      int p = atomicAdd(&lcur[bk[j]], 1);
      stage[p] = pk[j];
    }
  }
  __syncthreads();

  int tot = stot;
  for (int i = t; i < tot; i += 256){
    unsigned e = stage[i];
    int b = (int)(e >> 24);
    ebin[(size_t)b * BCAP + gbase[b] + (i - lex[b])] = e;
  }
}

__global__ __launch_bounds__(256) void k_bscan2(const int* __restrict__ gcnt, int* __restrict__ bbase,
                                                int* __restrict__ rowptr){
  __shared__ int sd[256];
  int t = threadIdx.x;
  int v = (t < NB2) ? gcnt[t] : 0;
  sd[t] = v; __syncthreads();
  for (int off = 1; off < 256; off <<= 1){
    int a = (t >= off) ? sd[t - off] : 0;
    __syncthreads();
    sd[t] += a; __syncthreads();
  }
  if (t < NB2) bbase[t] = sd[t] - v;
  if (t == NB2 - 1) rowptr[N_NODES] = sd[t];
}

__global__ __launch_bounds__(256) void k_bfin(const int* __restrict__ gcnt, const int* __restrict__ bbase,
                                              const unsigned* __restrict__ ebin,
                                              unsigned short* __restrict__ eid16,
                                              int* __restrict__ rowptr, int n){
  __shared__ int hist[256], lb[256], lcur[256];
  int t = threadIdx.x, b = blockIdx.x;
  int cb   = gcnt[b];
  int base = bbase[b];
  const unsigned* eb = &ebin[(size_t)b * BCAP];
  hist[t] = 0;
  __syncthreads();
  for (int idx = t; idx < cb; idx += 256) atomicAdd(&hist[(eb[idx] >> 16) & 255], 1);
  __syncthreads();
  lb[t] = hist[t];
  __syncthreads();
  for (int off = 1; off < 256; off <<= 1){
    int v = (t >= off) ? lb[t - off] : 0;
    __syncthreads();
    lb[t] += v; __syncthreads();
  }
  int ex = lb[t] - hist[t];
  lcur[t] = ex;
  int node = (b << 8) + t;
  if (node < n) rowptr[node] = base + ex;
  __syncthreads();
  for (int idx = t; idx < cb; idx += 256){
    unsigned e = eb[idx];
    int p = atomicAdd(&lcur[(e >> 16) & 255], 1);
    eid16[base + p] = (unsigned short)(e & 0xffffu);
  }
}

// ---------------- fused prep: all weight/input conversions in ONE kernel ----------------
// blocks [0,128)   : SAGE L0 weights  -> bth0/btl0 [col][256]
// blocks [128,256) : SAGE L1 weights  -> bth1/btl1
// blocks [256,320) : W1^T split       -> w1th/w1tl [64][64]
// blocks [320,448) : [W0u|W0v]^T split-> w0cth/w0ctl [128][128]
// blocks [448,...) : x -> split planes xh/xl (8 elems/thread)
__global__ __launch_bounds__(256) void k_prep(
    const float* __restrict__ ws0, const float* __restrict__ wn0,
    const float* __restrict__ ws1, const float* __restrict__ wn1,
    const float* __restrict__ mw0, const float* __restrict__ mw1,
    const float* __restrict__ X,
    unsigned short* __restrict__ bth0, unsigned short* __restrict__ btl0,
    unsigned short* __restrict__ bth1, unsigned short* __restrict__ btl1,
    unsigned short* __restrict__ w1th, unsigned short* __restrict__ w1tl,
    unsigned short* __restrict__ w0cth, unsigned short* __restrict__ w0ctl,
    unsigned short* __restrict__ XH, unsigned short* __restrict__ XL)
{
  int b = blockIdx.x, t = threadIdx.x;
  if (b < 256){
    int col = b & 127;
    const float* wsp = (b < 128) ? ws0 : ws1;
    const float* wnp = (b < 128) ? wn0 : wn1;
    unsigned short* th = (b < 128) ? bth0 : bth1;
    unsigned short* tl = (b < 128) ? btl0 : btl1;
    float v = (t < 128) ? wsp[t * D + col] : wnp[(t - 128) * D + col];
    unsigned short hi = f2bf_rn(v);
    th[col * 256 + t] = hi;
    tl[col * 256 + t] = f2bf_rn(v - bf2f(hi));
  } else if (b < 320){
    if (t < 64){
      int col = b - 256;
      float v = mw1[t * 64 + col];
      unsigned short hi = f2bf_rn(v);
      w1th[col * 64 + t] = hi;
      w1tl[col * 64 + t] = f2bf_rn(v - bf2f(hi));
    }
  } else if (b < 448){
    if (t < 128){
      int col = b - 320;
      float v = (col < 64) ? mw0[t * 64 + col] : mw0[(128 + t) * 64 + (col - 64)];
      unsigned short hi = f2bf_rn(v);
      w0cth[col * 128 + t] = hi;
      w0ctl[col * 128 + t] = f2bf_rn(v - bf2f(hi));
    }
  } else {
    int i = (b - 448) * 256 + t;            // 8 floats per thread
    if (i < N_NODES * D / 8){
      const float4* xp = reinterpret_cast<const float4*>(&X[(size_t)i * 8]);
      float4 v0 = xp[0], v1 = xp[1];
      uint4 h, l;
      split2(v0.x, v0.y, h.x, l.x);
      split2(v0.z, v0.w, h.y, l.y);
      split2(v1.x, v1.y, h.z, l.z);
      split2(v1.z, v1.w, h.w, l.w);
      *reinterpret_cast<uint4*>(&XH[(size_t)i * 8]) = h;
      *reinterpret_cast<uint4*>(&XL[(size_t)i * 8]) = l;
    }
  }
}

// ---------------- mean aggregation: bf16 gather (hi plane), split-bf16 output ----------------
__global__ __launch_bounds__(256) void k_agg_bf(const unsigned short* __restrict__ XB,
                                                const int* __restrict__ rowptr, const unsigned short* __restrict__ eid,
                                                unsigned short* __restrict__ AGH, unsigned short* __restrict__ AGL,
                                                int n){
  int g = blockIdx.x * 8 + (threadIdx.x >> 5);   // node
  int l = threadIdx.x & 31;                      // 4-bf16 chunk
  if (g >= n) return;
  int e0 = rowptr[g], e1 = rowptr[g + 1];
  float4 a0 = make_float4(0.f,0.f,0.f,0.f);
  float4 a1 = make_float4(0.f,0.f,0.f,0.f);
  float4 a2 = make_float4(0.f,0.f,0.f,0.f);
  float4 a3 = make_float4(0.f,0.f,0.f,0.f);
  int e = e0;
  for (; e + 4 <= e1; e += 4){
    int s0 = eid[e], s1 = eid[e + 1], s2 = eid[e + 2], s3 = eid[e + 3];
    ushort4 u0 = *reinterpret_cast<const ushort4*>(&XB[(size_t)s0 * D + l * 4]);
    ushort4 u1 = *reinterpret_cast<const ushort4*>(&XB[(size_t)s1 * D + l * 4]);
    ushort4 u2 = *reinterpret_cast<const ushort4*>(&XB[(size_t)s2 * D + l * 4]);
    ushort4 u3 = *reinterpret_cast<const ushort4*>(&XB[(size_t)s3 * D + l * 4]);
    float4 f0 = bf4f(u0), f1 = bf4f(u1), f2 = bf4f(u2), f3 = bf4f(u3);
    a0.x += f0.x; a0.y += f0.y; a0.z += f0.z; a0.w += f0.w;
    a1.x += f1.x; a1.y += f1.y; a1.z += f1.z; a1.w += f1.w;
    a2.x += f2.x; a2.y += f2.y; a2.z += f2.z; a2.w += f2.w;
    a3.x += f3.x; a3.y += f3.y; a3.z += f3.z; a3.w += f3.w;
  }
  for (; e < e1; ++e){
    int s0 = eid[e];
    ushort4 u0 = *reinterpret_cast<const ushort4*>(&XB[(size_t)s0 * D + l * 4]);
    float4 f0 = bf4f(u0);
    a0.x += f0.x; a0.y += f0.y; a0.z += f0.z; a0.w += f0.w;
  }
  float sc = 1.f / fmaxf((float)(e1 - e0), 1.f);
  float ox = (a0.x + a1.x + a2.x + a3.x) * sc;
  float oy = (a0.y + a1.y + a2.y + a3.y) * sc;
  float oz = (a0.z + a1.z + a2.z + a3.z) * sc;
  float ow = (a0.w + a1.w + a2.w + a3.w) * sc;
  uint2 h, lo_;
  split2(ox, oy, h.x, lo_.x);
  split2(oz, ow, h.y, lo_.y);
  *reinterpret_cast<uint2*>(&AGH[(size_t)g * D + l * 4]) = h;
  *reinterpret_cast<uint2*>(&AGL[(size_t)g * D + l * 4]) = lo_;
}

// ---------------- SAGE layer via split-bf16 MFMA (all-pre-split inputs) ----------------
// A-operand k<128 from A0H/A0L, k>=128 from A1H/A1L — staging is straight
// 16B copies (the former per-step split8 VALU chain is gone; producers
// pre-split). Output: split-bf16 planes only (no fp32 H anywhere).
__global__ __launch_bounds__(256) void k_sage_mfma(
    const unsigned short* __restrict__ A0H, const unsigned short* __restrict__ A0L,
    const unsigned short* __restrict__ A1H, const unsigned short* __restrict__ A1L,
    const unsigned short* __restrict__ BTH, const unsigned short* __restrict__ BTL,
    const float* __restrict__ Bb, const float* __restrict__ GM, const float* __restrict__ BT,
    const float* __restrict__ RM, const float* __restrict__ RV,
    unsigned short* __restrict__ HBH, unsigned short* __restrict__ HBL,
    int n, int donan)
{
  __shared__ unsigned short Ah[64 * 40];
  __shared__ unsigned short Al[64 * 40];
  __shared__ unsigned short Bh[128 * 40];
  __shared__ unsigned short Bl[128 * 40];

  int t  = threadIdx.x;
  int l  = t & 63;
  int wv = t >> 6;
  int lm = l & 15;
  int lk = l >> 4;
  int node0 = blockIdx.x * 64;

  f32x4 acc[8];
  #pragma unroll
  for (int f = 0; f < 8; ++f) acc[f] = (f32x4){0.f, 0.f, 0.f, 0.f};

  for (int step = 0; step < 8; ++step){
    int k0 = step * 32;
    const unsigned short* srcH = (step < 4) ? A0H : A1H;
    const unsigned short* srcL = (step < 4) ? A0L : A1L;
    int koff = (step < 4) ? k0 : (k0 - 128);

    __syncthreads();
    {  // stage A: 64 rows x 32 k, 16B copies (256 threads cover 64x4 chunks)
      int row = t >> 2, q = t & 3;
      int node = min(node0 + row, n - 1);
      *reinterpret_cast<uint4*>(&Ah[row * 40 + q * 8]) =
          *reinterpret_cast<const uint4*>(&srcH[(size_t)node * D + koff + q * 8]);
      *reinterpret_cast<uint4*>(&Al[row * 40 + q * 8]) =
          *reinterpret_cast<const uint4*>(&srcL[(size_t)node * D + koff + q * 8]);
    }
    #pragma unroll
    for (int i = 0; i < 2; ++i){
      int c   = t + i * 256;
      int col = c >> 2, q = c & 3;
      *reinterpret_cast<uint4*>(&Bh[col * 40 + q * 8]) =
          *reinterpret_cast<const uint4*>(&BTH[col * 256 + k0 + q * 8]);
      *reinterpret_cast<uint4*>(&Bl[col * 40 + q * 8]) =
          *reinterpret_cast<const uint4*>(&BTL[col * 256 + k0 + q * 8]);
    }
    __syncthreads();

    bf16x8 afh = *reinterpret_cast<const bf16x8*>(&Ah[(wv * 16 + lm) * 40 + lk * 8]);
    bf16x8 afl = *reinterpret_cast<const bf16x8*>(&Al[(wv * 16 + lm) * 40 + lk * 8]);
    #pragma unroll
    for (int f = 0; f < 8; ++f){
      bf16x8 bfh = *reinterpret_cast<const bf16x8*>(&Bh[(f * 16 + lm) * 40 + lk * 8]);
      bf16x8 bfl = *reinterpret_cast<const bf16x8*>(&Bl[(f * 16 + lm) * 40 + lk * 8]);
      acc[f] = __builtin_amdgcn_mfma_f32_16x16x32_bf16(afh, bfh, acc[f], 0, 0, 0);
      acc[f] = __builtin_amdgcn_mfma_f32_16x16x32_bf16(afl, bfh, acc[f], 0, 0, 0);
      acc[f] = __builtin_amdgcn_mfma_f32_16x16x32_bf16(afh, bfl, acc[f], 0, 0, 0);
    }
  }

  #pragma unroll
  for (int f = 0; f < 8; ++f){
    int col = f * 16 + lm;
    float s  = GM[col] * rsqrtf(RV[col] + BN_EPS);
    float cj = (Bb[col] - RM[col]) * s + BT[col];
    #pragma unroll
    for (int r = 0; r < 4; ++r){
      int node = node0 + wv * 16 + lk * 4 + r;
      if (node < n){
        float v = lrelu(acc[f][r] * s + cj);
        if (donan && (v != v)) v = 1e-14f;
        unsigned short h16 = f2bf_rn(v);
        HBH[(size_t)node * D + col] = h16;
        HBL[(size_t)node * D + col] = f2bf_rn(v - bf2f(h16));
      }
    }
  }
}

// ---------------- P = h1 @ [W0u | W0v]  (dense GEMM, pre-split in/out) ----------------
__global__ __launch_bounds__(256) void k_pgemm(
    const unsigned short* __restrict__ HH, const unsigned short* __restrict__ HL,
    const unsigned short* __restrict__ WCH, const unsigned short* __restrict__ WCL,
    unsigned short* __restrict__ PH, unsigned short* __restrict__ PL, int n)
{
  __shared__ unsigned short Ah[64 * 40];
  __shared__ unsigned short Al[64 * 40];
  __shared__ unsigned short Bh[128 * 40];
  __shared__ unsigned short Bl[128 * 40];

  int t  = threadIdx.x;
  int l  = t & 63;
  int wv = t >> 6;
  int lm = l & 15;
  int lk = l >> 4;
  int node0 = blockIdx.x * 64;

  f32x4 acc[8];
  #pragma unroll
  for (int f = 0; f < 8; ++f) acc[f] = (f32x4){0.f, 0.f, 0.f, 0.f};

  for (int step = 0; step < 4; ++step){
    int k0 = step * 32;
    __syncthreads();
    {
      int row = t >> 2, q = t & 3;
      int node = min(node0 + row, n - 1);
      *reinterpret_cast<uint4*>(&Ah[row * 40 + q * 8]) =
          *reinterpret_cast<const uint4*>(&HH[(size_t)node * D + k0 + q * 8]);
      *reinterpret_cast<uint4*>(&Al[row * 40 + q * 8]) =
          *reinterpret_cast<const uint4*>(&HL[(size_t)node * D + k0 + q * 8]);
    }
    #pragma unroll
    for (int i = 0; i < 2; ++i){
      int c = t + i * 256;
      int col = c >> 2, q = c & 3;
      *reinterpret_cast<uint4*>(&Bh[col * 40 + q * 8]) =
          *reinterpret_cast<const uint4*>(&WCH[col * 128 + k0 + q * 8]);
      *reinterpret_cast<uint4*>(&Bl[col * 40 + q * 8]) =
          *reinterpret_cast<const uint4*>(&WCL[col * 128 + k0 + q * 8]);
    }
    __syncthreads();

    bf16x8 afh = *reinterpret_cast<const bf16x8*>(&Ah[(wv * 16 + lm) * 40 + lk * 8]);
    bf16x8 afl = *reinterpret_cast<const bf16x8*>(&Al[(wv * 16 + lm) * 40 + lk * 8]);
    #pragma unroll
    for (int f = 0; f < 8; ++f){
      bf16x8 bfh = *reinterpret_cast<const bf16x8*>(&Bh[(f * 16 + lm) * 40 + lk * 8]);
      bf16x8 bfl = *reinterpret_cast<const bf16x8*>(&Bl[(f * 16 + lm) * 40 + lk * 8]);
      acc[f] = __builtin_amdgcn_mfma_f32_16x16x32_bf16(afh, bfh, acc[f], 0, 0, 0);
      acc[f] = __builtin_amdgcn_mfma_f32_16x16x32_bf16(afl, bfh, acc[f], 0, 0, 0);
      acc[f] = __builtin_amdgcn_mfma_f32_16x16x32_bf16(afh, bfl, acc[f], 0, 0, 0);
    }
  }

  #pragma unroll
  for (int f = 0; f < 8; ++f){
    int col = f * 16 + lm;
    #pragma unroll
    for (int r = 0; r < 4; ++r){
      int node = node0 + wv * 16 + lk * 4 + r;
      if (node < n){
        float v = acc[f][r];
        unsigned short h16 = f2bf_rn(v);
        PH[(size_t)node * D + col] = h16;
        PL[(size_t)node * D + col] = f2bf_rn(v - bf2f(h16));
      }
    }
  }
}

__device__ __forceinline__ void proc2(unsigned uh, unsigned ul, unsigned vh, unsigned vl,
                                      float wfa, float wfb, float b0a, float b0b, float cfv,
                                      unsigned &ho, unsigned &lo_){
  float z0 = lrelu(bfu(uh) + bfu(ul) + bfu(vh) + bfu(vl) + cfv * wfa + b0a);
  float z1 = lrelu(bfh(uh) + bfh(ul) + bfh(vh) + bfh(vl) + cfv * wfb + b0b);
  split2(z0, z1, ho, lo_);
}

// ---------------- candidate MLP tail: gather P + L2 + L3 ----------------
__global__ __launch_bounds__(256) void k_mlp2(
    const unsigned short* __restrict__ PH, const unsigned short* __restrict__ PL,
    const int* __restrict__ cu, const int* __restrict__ cv, const float* __restrict__ cf,
    const float* __restrict__ mw0, const float* __restrict__ mb0,
    const unsigned short* __restrict__ W1H, const unsigned short* __restrict__ W1L,
    const float* __restrict__ mb1, const float* __restrict__ mw2, const float* __restrict__ mb2,
    float* __restrict__ y, int C)
{
  __shared__ unsigned short zh[4][32 * 72];
  __shared__ unsigned short zl[4][32 * 72];
  __shared__ float bw[64], ww[64];

  int t = threadIdx.x;
  int wv = t >> 6, l = t & 63, lm = l & 15, lk = l >> 4;
  int cl = l & 31, hsel = l >> 5;
  int candbase = blockIdx.x * 128 + wv * 32;

  if (t < 64){ bw[t] = mb0[t]; ww[t] = mw0[256 * 64 + t]; }
  __syncthreads();

  int cc = min(candbase + cl, C - 1);
  int nu = cu[cc], nv = cv[cc];
  float cfv = cf[cc];

  const uint4* puh = reinterpret_cast<const uint4*>(&PH[(size_t)nu * D + hsel * 32]);
  const uint4* pul = reinterpret_cast<const uint4*>(&PL[(size_t)nu * D + hsel * 32]);
  const uint4* pvh = reinterpret_cast<const uint4*>(&PH[(size_t)nv * D + 64 + hsel * 32]);
  const uint4* pvl = reinterpret_cast<const uint4*>(&PL[(size_t)nv * D + 64 + hsel * 32]);
  uint4 uh0 = puh[0], uh1 = puh[1], uh2 = puh[2], uh3 = puh[3];
  uint4 ul0 = pul[0], ul1 = pul[1], ul2 = pul[2], ul3 = pul[3];
  uint4 vh0 = pvh[0], vh1 = pvh[1], vh2 = pvh[2], vh3 = pvh[3];
  uint4 vl0 = pvl[0], vl1 = pvl[1], vl2 = pvl[2], vl3 = pvl[3];

  int colb = hsel * 32;
  unsigned short* zhr = &zh[wv][cl * 72];
  unsigned short* zlr = &zl[wv][cl * 72];
  #define PROC_W(UH, UL, VH, VL, CO) { \
    unsigned ho, lo_; \
    proc2(UH, UL, VH, VL, ww[colb + (CO)], ww[colb + (CO) + 1], bw[colb + (CO)], bw[colb + (CO) + 1], cfv, ho, lo_); \
    *reinterpret_cast<unsigned*>(&zhr[colb + (CO)]) = ho; \
    *reinterpret_cast<unsigned*>(&zlr[colb + (CO)]) = lo_; }
  PROC_W(uh0.x, ul0.x, vh0.x, vl0.x, 0)  PROC_W(uh0.y, ul0.y, vh0.y, vl0.y, 2)
  PROC_W(uh0.z, ul0.z, vh0.z, vl0.z, 4)  PROC_W(uh0.w, ul0.w, vh0.w, vl0.w, 6)
  PROC_W(uh1.x, ul1.x, vh1.x, vl1.x, 8)  PROC_W(uh1.y, ul1.y, vh1.y, vl1.y, 10)
  PROC_W(uh1.z, ul1.z, vh1.z, vl1.z, 12) PROC_W(uh1.w, ul1.w, vh1.w, vl1.w, 14)
  PROC_W(uh2.x, ul2.x, vh2.x, vl2.x, 16) PROC_W(uh2.y, ul2.y, vh2.y, vl2.y, 18)
  PROC_W(uh2.z, ul2.z, vh2.z, vl2.z, 20) PROC_W(uh2.w, ul2.w, vh2.w, vl2.w, 22)
  PROC_W(uh3.x, ul3.x, vh3.x, vl3.x, 24) PROC_W(uh3.y, ul3.y, vh3.y, vl3.y, 26)
  PROC_W(uh3.z, ul3.z, vh3.z, vl3.z, 28) PROC_W(uh3.w, ul3.w, vh3.w, vl3.w, 30)
  #undef PROC_W

  int kbase = lk * 8;
  f32x4 a2[2][4];
  #pragma unroll
  for (int m = 0; m < 2; ++m)
    #pragma unroll
    for (int f = 0; f < 4; ++f) a2[m][f] = (f32x4){0.f, 0.f, 0.f, 0.f};

  #pragma unroll
  for (int s2 = 0; s2 < 2; ++s2){
    int kk = s2 * 32 + kbase;
    bf16x8 azh0 = *reinterpret_cast<const bf16x8*>(&zh[wv][(0 * 16 + lm) * 72 + kk]);
    bf16x8 azl0 = *reinterpret_cast<const bf16x8*>(&zl[wv][(0 * 16 + lm) * 72 + kk]);
    bf16x8 azh1 = *reinterpret_cast<const bf16x8*>(&zh[wv][(1 * 16 + lm) * 72 + kk]);
    bf16x8 azl1 = *reinterpret_cast<const bf16x8*>(&zl[wv][(1 * 16 + lm) * 72 + kk]);
    #pragma unroll
    for (int f = 0; f < 4; ++f){
      int col = f * 16 + lm;
      bf16x8 bh = *reinterpret_cast<const bf16x8*>(&W1H[(size_t)col * 64 + kk]);
      bf16x8 bl = *reinterpret_cast<const bf16x8*>(&W1L[(size_t)col * 64 + kk]);
      a2[0][f] = __builtin_amdgcn_mfma_f32_16x16x32_bf16(azh0, bh, a2[0][f], 0, 0, 0);
      a2[0][f] = __builtin_amdgcn_mfma_f32_16x16x32_bf16(azl0, bh, a2[0][f], 0, 0, 0);
      a2[0][f] = __builtin_amdgcn_mfma_f32_16x16x32_bf16(azh0, bl, a2[0][f], 0, 0, 0);
      a2[1][f] = __builtin_amdgcn_mfma_f32_16x16x32_bf16(azh1, bh, a2[1][f], 0, 0, 0);
      a2[1][f] = __builtin_amdgcn_mfma_f32_16x16x32_bf16(azl1, bh, a2[1][f], 0, 0, 0);
      a2[1][f] = __builtin_amdgcn_mfma_f32_16x16x32_bf16(azh1, bl, a2[1][f], 0, 0, 0);
    }
  }

  float p00 = 0.f, p01 = 0.f, p02 = 0.f, p03 = 0.f;
  float p10 = 0.f, p11 = 0.f, p12 = 0.f, p13 = 0.f;
  #pragma unroll
  for (int f = 0; f < 4; ++f){
    int col = f * 16 + lm;
    float b1v = mb1[col];
    float w2v = mw2[col];
    p00 = fmaf(lrelu(a2[0][f][0] + b1v), w2v, p00);
    p01 = fmaf(lrelu(a2[0][f][1] + b1v), w2v, p01);
    p02 = fmaf(lrelu(a2[0][f][2] + b1v), w2v, p02);
    p03 = fmaf(lrelu(a2[0][f][3] + b1v), w2v, p03);
    p10 = fmaf(lrelu(a2[1][f][0] + b1v), w2v, p10);
    p11 = fmaf(lrelu(a2[1][f][1] + b1v), w2v, p11);
    p12 = fmaf(lrelu(a2[1][f][2] + b1v), w2v, p12);
    p13 = fmaf(lrelu(a2[1][f][3] + b1v), w2v, p13);
  }
  #pragma unroll
  for (int off = 1; off < 16; off <<= 1){
    p00 += __shfl_xor(p00, off); p01 += __shfl_xor(p01, off);
    p02 += __shfl_xor(p02, off); p03 += __shfl_xor(p03, off);
    p10 += __shfl_xor(p10, off); p11 += __shfl_xor(p11, off);
    p12 += __shfl_xor(p12, off); p13 += __shfl_xor(p13, off);
  }
  if (lm == 0){
    float b2 = mb2[0];
    int base0 = candbase + lk * 4;
    int base1 = candbase + 16 + lk * 4;
    if (base0 + 0 < C) y[base0 + 0] = p00 + b2;
    if (base0 + 1 < C) y[base0 + 1] = p01 + b2;
    if (base0 + 2 < C) y[base0 + 2] = p02 + b2;
    if (base0 + 3 < C) y[base0 + 3] = p03 + b2;
    if (base1 + 0 < C) y[base1 + 0] = p10 + b2;
    if (base1 + 1 < C) y[base1 + 1] = p11 + b2;
    if (base1 + 2 < C) y[base1 + 2] = p12 + b2;
    if (base1 + 3 < C) y[base1 + 3] = p13 + b2;
  }
}

// ---------------- softmax over C logits ----------------
__global__ __launch_bounds__(256) void k_red1(const float* __restrict__ y,
                                              float* __restrict__ bmax, float* __restrict__ bsum, int C){
  __shared__ float sm[4];
  __shared__ float ss[4];
  int t = threadIdx.x;
  float m = -3.4e38f;
  for (int i = blockIdx.x * 256 + t; i < C; i += gridDim.x * 256) m = fmaxf(m, y[i]);
  for (int o = 32; o; o >>= 1) m = fmaxf(m, __shfl_xor(m, o));
  if ((t & 63) == 0) sm[t >> 6] = m;
  __syncthreads();
  float bm = fmaxf(fmaxf(sm[0], sm[1]), fmaxf(sm[2], sm[3]));
  float s = 0.f;
  for (int i = blockIdx.x * 256 + t; i < C; i += gridDim.x * 256) s += expf(y[i] - bm);
  for (int o = 32; o; o >>= 1) s += __shfl_xor(s, o);
  if ((t & 63) == 0) ss[t >> 6] = s;
  __syncthreads();
  if (t == 0){ bmax[blockIdx.x] = bm; bsum[blockIdx.x] = ss[0] + ss[1] + ss[2] + ss[3]; }
}

__global__ __launch_bounds__(256) void k_red2(const float* __restrict__ bmax, const float* __restrict__ bsum,
                                              float* __restrict__ g, int nb){
  __shared__ float sm[4];
  __shared__ float ss[4];
  int t = threadIdx.x;
  float m0 = (t < nb) ? bmax[t] : -3.4e38f;
  float m = m0;
  for (int o = 32; o; o >>= 1) m = fmaxf(m, __shfl_xor(m, o));
  if ((t & 63) == 0) sm[t >> 6] = m;
  __syncthreads();
  float gm = fmaxf(fmaxf(sm[0], sm[1]), fmaxf(sm[2], sm[3]));
  float s = (t < nb) ? bsum[t] * expf(m0 - gm) : 0.f;
  for (int o = 32; o; o >>= 1) s += __shfl_xor(s, o);
  if ((t & 63) == 0) ss[t >> 6] = s;
  __syncthreads();
  if (t == 0){ g[0] = gm; g[1] = 1.f / (ss[0] + ss[1] + ss[2] + ss[3]); }
}

__global__ __launch_bounds__(256) void k_red3(const float* __restrict__ y, const float* __restrict__ g,
                                              float* __restrict__ out, int C){
  int i = blockIdx.x * 256 + threadIdx.x;
  if (i < C) out[i] = expf(y[i] - g[0]) * g[1];
}

extern "C" void kernel_launch(void* const* d_in, const int* in_sizes, int n_in,
                              void* d_out, int out_size, void* d_ws, size_t ws_size,
                              hipStream_t stream)
{
  const float* x   = (const float*)d_in[0];
  const int*   src = (const int*)  d_in[1];
  const int*   dst = (const int*)  d_in[2];
  const int*   cu  = (const int*)  d_in[3];
  const int*   cv  = (const int*)  d_in[4];
  const float* cf  = (const float*)d_in[5];
  const float* ws0 = (const float*)d_in[6];
  const float* wn0 = (const float*)d_in[7];
  const float* b0  = (const float*)d_in[8];
  const float* g0  = (const float*)d_in[9];
  const float* be0 = (const float*)d_in[10];
  const float* rm0 = (const float*)d_in[11];
  const float* rv0 = (const float*)d_in[12];
  const float* ws1 = (const float*)d_in[13];
  const float* wn1 = (const float*)d_in[14];
  const float* b1  = (const float*)d_in[15];
  const float* g1  = (const float*)d_in[16];
  const float* be1 = (const float*)d_in[17];
  const float* rm1 = (const float*)d_in[18];
  const float* rv1 = (const float*)d_in[19];
  const float* mw0 = (const float*)d_in[20];
  const float* mb0 = (const float*)d_in[21];
  const float* mw1 = (const float*)d_in[22];
  const float* mb1 = (const float*)d_in[23];
  const float* mw2 = (const float*)d_in[24];
  const float* mb2 = (const float*)d_in[25];

  float* out = (float*)d_out;   // [C] y then [C] softmax

  char* w = (char*)d_ws;
  char* regA = w; w += (size_t)N_NODES * D * 4;   // agh/agl -> later ph/pl
  char* regB = w; w += (size_t)N_NODES * D * 4;   // ebin -> hb0h/hb0l
  char* regC = w; w += (size_t)N_NODES * D * 4;   // xh/xl -> hb1h/hb1l
  int* cnt     = (int*)w;   w += (size_t)N_NODES * 4;          // -> SAGE weights L0
  int* rowptr  = (int*)w;   w += (size_t)(N_NODES + 1) * 4;
  int* cur     = (int*)w;   w += (size_t)N_NODES * 4;          // -> SAGE weights L1
  int* eid     = (int*)w;   w += (size_t)N_EDGES * 4;          // holds eid16
  int* gcnt    = (int*)w;   w += (size_t)(NB2 + 8) * 4;
  int* bbase   = (int*)w;   w += (size_t)(NB2 + 1) * 4;
  float* bmax  = (float*)w; w += 256 * 4;
  float* bsumF = (float*)w; w += 256 * 4;
  float* gred  = (float*)w; w += 2 * 4;
  unsigned short* w1th  = (unsigned short*)w; w += (size_t)64 * 64 * 2;
  unsigned short* w1tl  = (unsigned short*)w; w += (size_t)64 * 64 * 2;
  unsigned short* w0cth = (unsigned short*)w; w += (size_t)128 * 128 * 2;
  unsigned short* w0ctl = (unsigned short*)w; w += (size_t)128 * 128 * 2;

  unsigned short* eid16 = (unsigned short*)eid;

  // regB: ebin (CSR phase, 3.7MB) -> hb0h/hb0l (sage0 output, agg1+sage1 input)
  unsigned* ebin = (unsigned*)regB;
  unsigned short* hb0h = (unsigned short*)regB;
  unsigned short* hb0l = hb0h + (size_t)N_NODES * D;
  // regC: xh/xl (prep -> sage0) -> hb1h/hb1l (sage1 output -> pgemm)
  unsigned short* xh   = (unsigned short*)regC;
  unsigned short* xl   = xh + (size_t)N_NODES * D;
  unsigned short* hb1h = (unsigned short*)regC;
  unsigned short* hb1l = hb1h + (size_t)N_NODES * D;
  // regA: agh/agl (agg -> sage) -> ph/pl (pgemm output -> mlp2)
  unsigned short* agh = (unsigned short*)regA;
  unsigned short* agl = agh + (size_t)N_NODES * D;
  unsigned short* pbh = (unsigned short*)regA;
  unsigned short* pbl = pbh + (size_t)N_NODES * D;

  unsigned short* bth0 = (unsigned short*)cnt;
  unsigned short* btl0 = bth0 + 128 * 256;
  unsigned short* bth1 = (unsigned short*)cur;
  unsigned short* btl1 = bth1 + 128 * 256;

  // ---- CSR build ----
  hipMemsetAsync(gcnt, 0, (size_t)NB2 * 4, stream);
  k_bin   <<<NTILE, 256, 0, stream>>>(src, dst, gcnt, ebin, N_EDGES);
  k_bscan2<<<1, 256, 0, stream>>>(gcnt, bbase, rowptr);
  k_bfin  <<<NB2, 256, 0, stream>>>(gcnt, bbase, ebin, eid16, rowptr, N_NODES);

  // ---- fused conversions (one kernel) ----
  int PREPB = 448 + (N_NODES * D / 8 + 255) / 256;
  k_prep<<<PREPB, 256, 0, stream>>>(ws0, wn0, ws1, wn1, mw0, mw1, x,
      bth0, btl0, bth1, btl1, w1th, w1tl, w0cth, w0ctl, xh, xl);

  int GB = (N_NODES + 63) / 64;     // 782
  k_agg_bf<<<(N_NODES + 7) / 8, 256, 0, stream>>>(xh, rowptr, eid16, agh, agl, N_NODES);
  k_sage_mfma<<<GB, 256, 0, stream>>>(xh, xl, agh, agl, bth0, btl0,
                                      b0, g0, be0, rm0, rv0, hb0h, hb0l, N_NODES, 0);
  k_agg_bf<<<(N_NODES + 7) / 8, 256, 0, stream>>>(hb0h, rowptr, eid16, agh, agl, N_NODES);
  k_sage_mfma<<<GB, 256, 0, stream>>>(hb0h, hb0l, agh, agl, bth1, btl1,
                                      b1, g1, be1, rm1, rv1, hb1h, hb1l, N_NODES, 1);

  k_pgemm<<<GB, 256, 0, stream>>>(hb1h, hb1l, w0cth, w0ctl, pbh, pbl, N_NODES);

  k_mlp2<<<(N_CAND + 127) / 128, 256, 0, stream>>>(pbh, pbl, cu, cv, cf,
      mw0, mb0, w1th, w1tl, mb1, mw2, mb2, out, N_CAND);

  k_red1<<<256, 256, 0, stream>>>(out, bmax, bsumF, N_CAND);
  k_red2<<<1, 256, 0, stream>>>(bmax, bsumF, gred, 256);
  k_red3<<<(N_CAND + 255) / 256, 256, 0, stream>>>(out, gred, out + N_CAND, N_CAND);
}